// Round 1
// baseline (6239.938 us; speedup 1.0000x reference)
//
#include <hip/hip_runtime.h>
#include <math.h>

#define NN 30000
#define EE 960000
#define IN_ 128
#define DD 256
#define CC 40
#define EPS 1e-5f

// ---------------------------------------------------------------------------
// Generic tiled f32 GEMM: C[n, colbase+c] = act(sum_k A[n,k]*W[colbase+c, k] + bias)
// BM=64 nodes, BN=64 cols, BK=32. block = 256 threads, 4x4 register tile.
// Optionally accumulates per-column sum/sumsq of the OUTPUT (post-activation).
// act: 0=none, 1=relu, 2=leaky_relu(0.01)
// ---------------------------------------------------------------------------
__global__ __launch_bounds__(256) void gemm_tile(
    const float* __restrict__ A, int lda,
    const float* __restrict__ W, int ldw,
    const float* __restrict__ bias,
    float* __restrict__ Cout, int ldc,
    int Nrows, int K, int act,
    float* __restrict__ ssum, float* __restrict__ ssq)
{
    __shared__ float At[32][68];   // [k][node]
    __shared__ float Wt[32][68];   // [k][col]
    const int t = threadIdx.x;
    const int nbase = blockIdx.x * 64;
    const int colbase = blockIdx.y * 64;
    const int tm = t & 15;         // node quad
    const int td = t >> 4;         // col quad
    float acc[4][4] = {};

    for (int kb = 0; kb < K; kb += 32) {
        __syncthreads();
#pragma unroll
        for (int rep = 0; rep < 8; ++rep) {
            int e = rep * 256 + t;
            int nl = e >> 5, kl = e & 31;
            int n = nbase + nl;
            float av = (n < Nrows) ? A[(size_t)n * lda + kb + kl] : 0.f;
            At[kl][nl] = av;
            Wt[kl][nl] = W[(size_t)(colbase + nl) * ldw + kb + kl];
        }
        __syncthreads();
#pragma unroll
        for (int k = 0; k < 32; ++k) {
            float4 a4 = *(const float4*)&At[k][tm * 4];
            float4 w4 = *(const float4*)&Wt[k][td * 4];
            float av[4] = {a4.x, a4.y, a4.z, a4.w};
            float wv[4] = {w4.x, w4.y, w4.z, w4.w};
#pragma unroll
            for (int m = 0; m < 4; ++m)
#pragma unroll
                for (int p = 0; p < 4; ++p)
                    acc[m][p] += av[m] * wv[p];
        }
    }

    float cs[4] = {}, cq[4] = {};
#pragma unroll
    for (int m = 0; m < 4; ++m) {
        int n = nbase + tm * 4 + m;
        if (n < Nrows) {
#pragma unroll
            for (int p = 0; p < 4; ++p) {
                float v = acc[m][p];
                if (bias) v += bias[colbase + td * 4 + p];
                if (act == 1) v = fmaxf(v, 0.f);
                else if (act == 2) v = (v > 0.f) ? v : 0.01f * v;
                Cout[(size_t)n * ldc + colbase + td * 4 + p] = v;
                cs[p] += v;
                cq[p] += v * v;
            }
        }
    }
    if (ssum) {
#pragma unroll
        for (int p = 0; p < 4; ++p) {
            float s1 = cs[p], s2 = cq[p];
            for (int off = 8; off >= 1; off >>= 1) {
                s1 += __shfl_down(s1, off, 16);
                s2 += __shfl_down(s2, off, 16);
            }
            if (tm == 0) {
                atomicAdd(&ssum[colbase + td * 4 + p], s1);
                atomicAdd(&ssq[colbase + td * 4 + p], s2);
            }
        }
    }
}

// ---------------------------------------------------------------------------
// Big fused GEMM: H[n,d] = sum_{i,j} xdes[n,i]*agg[n,j]*Wp[d, i*64+j]
// xdes[n,i] = a1[i]*y1[n,i] + c1[i] (BN folded, recomputed on the fly).
// Tile: 64 nodes x 64 d per block, K=4096 as outer i(64) x inner j(64).
// ---------------------------------------------------------------------------
__global__ __launch_bounds__(256) void fog_biggemm(
    const float* __restrict__ y1, const float* __restrict__ a1, const float* __restrict__ c1,
    const float* __restrict__ agg, const float* __restrict__ Wp,
    float* __restrict__ H, int Nrows,
    float* __restrict__ ssum, float* __restrict__ ssq)
{
    __shared__ float xd[64][68];   // [i][node]
    __shared__ float ag[64][68];   // [j][node]
    __shared__ float Wt[64][68];   // [j][d]
    const int t = threadIdx.x;
    const int nbase = blockIdx.x * 64;
    const int dbase = blockIdx.y * 64;
    const int tm = t & 15;
    const int td = t >> 4;

#pragma unroll
    for (int rep = 0; rep < 16; ++rep) {
        int e = rep * 256 + t;
        int nl = e >> 6, f = e & 63;
        int n = nbase + nl;
        float yv = 0.f, av = 0.f;
        if (n < Nrows) { yv = y1[(size_t)n * 64 + f]; av = agg[(size_t)n * 64 + f]; }
        xd[f][nl] = a1[f] * yv + c1[f];
        ag[f][nl] = av;
    }

    float acc[4][4] = {};
    for (int i = 0; i < 64; ++i) {
        __syncthreads();
#pragma unroll
        for (int rep = 0; rep < 16; ++rep) {
            int e = rep * 256 + t;
            int dl = e >> 6, j = e & 63;
            Wt[j][dl] = Wp[(size_t)(dbase + dl) * 4096 + i * 64 + j];
        }
        __syncthreads();
        float4 ax4 = *(const float4*)&xd[i][tm * 4];
        float axv[4] = {ax4.x, ax4.y, ax4.z, ax4.w};
#pragma unroll 8
        for (int j = 0; j < 64; ++j) {
            float4 g4 = *(const float4*)&ag[j][tm * 4];
            float4 w4 = *(const float4*)&Wt[j][td * 4];
            float gv[4] = {g4.x, g4.y, g4.z, g4.w};
            float wv[4] = {w4.x, w4.y, w4.z, w4.w};
#pragma unroll
            for (int m = 0; m < 4; ++m) {
                float tmm = axv[m] * gv[m];
#pragma unroll
                for (int p = 0; p < 4; ++p)
                    acc[m][p] += tmm * wv[p];
            }
        }
    }

    float cs[4] = {}, cq[4] = {};
#pragma unroll
    for (int m = 0; m < 4; ++m) {
        int n = nbase + tm * 4 + m;
        if (n < Nrows) {
#pragma unroll
            for (int p = 0; p < 4; ++p) {
                float v = acc[m][p];
                H[(size_t)n * 256 + dbase + td * 4 + p] = v;
                cs[p] += v;
                cq[p] += v * v;
            }
        }
    }
    if (ssum) {
#pragma unroll
        for (int p = 0; p < 4; ++p) {
            float s1 = cs[p], s2 = cq[p];
            for (int off = 8; off >= 1; off >>= 1) {
                s1 += __shfl_down(s1, off, 16);
                s2 += __shfl_down(s2, off, 16);
            }
            if (tm == 0) {
                atomicAdd(&ssum[dbase + td * 4 + p], s1);
                atomicAdd(&ssq[dbase + td * 4 + p], s2);
            }
        }
    }
}

// ---------------------------------------------------------------------------
// Edge scatter: agg[dst_e, :] += a2*y2[src_e, :] + c2  (BN2 applied on the fly)
// One thread per (edge, 4-float chunk): E*16 threads.
// ---------------------------------------------------------------------------
__global__ void scatter_edges(const int* __restrict__ src, const int* __restrict__ dst,
                              const float* __restrict__ y2,
                              const float* __restrict__ a2, const float* __restrict__ c2,
                              float* __restrict__ agg)
{
    long long idx = (long long)blockIdx.x * blockDim.x + threadIdx.x;
    if (idx >= (long long)EE * 16) return;
    int e = (int)(idx >> 4);
    int q = (int)(idx & 15);
    int s = src[e], d = dst[e];
    float4 v = *(const float4*)&y2[(size_t)s * 64 + q * 4];
    float4 a4 = *(const float4*)&a2[q * 4];
    float4 c4 = *(const float4*)&c2[q * 4];
    atomicAdd(&agg[(size_t)d * 64 + q * 4 + 0], a4.x * v.x + c4.x);
    atomicAdd(&agg[(size_t)d * 64 + q * 4 + 1], a4.y * v.y + c4.y);
    atomicAdd(&agg[(size_t)d * 64 + q * 4 + 2], a4.z * v.z + c4.z);
    atomicAdd(&agg[(size_t)d * 64 + q * 4 + 3], a4.w * v.w + c4.w);
}

// ---------------------------------------------------------------------------
// BN fold: a = g*rsqrt(var+eps), c = b - mean*a
// ---------------------------------------------------------------------------
__global__ void fold_bn(const float* __restrict__ ssum, const float* __restrict__ ssq,
                        const float* __restrict__ g, const float* __restrict__ b,
                        float* __restrict__ a, float* __restrict__ c, int len, float invN)
{
    int i = blockIdx.x * blockDim.x + threadIdx.x;
    if (i < len) {
        float m = ssum[i] * invN;
        float v = ssq[i] * invN - m * m;
        float s = g[i] * rsqrtf(v + EPS);
        a[i] = s;
        c[i] = b[i] - m * s;
    }
}

// Fold BN1 affine into W2: W2f[j,i] = W2[j,i]*a1[i], b2f[j] = sum_i W2[j,i]*c1[i]
__global__ void fold_w2(const float* __restrict__ W2, const float* __restrict__ a1,
                        const float* __restrict__ c1,
                        float* __restrict__ W2f, float* __restrict__ b2f)
{
    int j = threadIdx.x;   // 64 threads
    float bb = 0.f;
    for (int i = 0; i < 64; ++i) {
        float w = W2[j * 64 + i];
        W2f[j * 64 + i] = w * a1[i];
        bb += w * c1[i];
    }
    b2f[j] = bb;
}

// ---------------------------------------------------------------------------
// JK epilogue. mode 0: x=relu(ah*h+ch); xbuf=x; s=x
//              mode 1: x=relu(ah*h+ch); xbuf=x; s+=x
//              mode 2: s += h
// (xbuf may alias Hh — elementwise in-place is safe)
// ---------------------------------------------------------------------------
__global__ void bn_relu_jk(const float* __restrict__ Hh,
                           const float* __restrict__ ah, const float* __restrict__ ch,
                           float* __restrict__ s, float* __restrict__ xbuf, int mode)
{
    long long idx = (long long)blockIdx.x * blockDim.x + threadIdx.x;
    if (idx >= (long long)NN * DD) return;
    int dcol = (int)(idx & 255);
    float v = Hh[idx];
    if (mode < 2) {
        v = ah[dcol] * v + ch[dcol];
        v = fmaxf(v, 0.f);
        xbuf[idx] = v;
        s[idx] = (mode == 0) ? v : s[idx] + v;
    } else {
        s[idx] += v;
    }
}

// ---------------------------------------------------------------------------
// Final head: logits = hid @ Wm2.T + bm2, then row log_softmax, write d_out.
// Block handles 64 nodes; 4 threads/node x 10 classes each. Wm2 in LDS.
// ---------------------------------------------------------------------------
__global__ __launch_bounds__(256) void mlp2_lsm(const float* __restrict__ hid,
                                                const float* __restrict__ Wm2,
                                                const float* __restrict__ bm2,
                                                float* __restrict__ out, int Nrows)
{
    __shared__ float Wl[40][257];
    __shared__ float bl[40];
    const int t = threadIdx.x;
    for (int e = t; e < 40 * 256; e += 256) {
        int c = e >> 8, k = e & 255;
        Wl[c][k] = Wm2[e];
    }
    if (t < 40) bl[t] = bm2[t];
    __syncthreads();

    int node = blockIdx.x * 64 + (t >> 2);
    int sub = t & 3;
    if (node >= Nrows) return;

    float acc[10];
#pragma unroll
    for (int r = 0; r < 10; ++r) acc[r] = bl[sub * 10 + r];
    const float* hrow = &hid[(size_t)node * 256];
    for (int k = 0; k < 256; k += 4) {
        float4 h4 = *(const float4*)&hrow[k];
        float hv[4] = {h4.x, h4.y, h4.z, h4.w};
#pragma unroll
        for (int kk = 0; kk < 4; ++kk)
#pragma unroll
            for (int r = 0; r < 10; ++r)
                acc[r] += hv[kk] * Wl[sub * 10 + r][k + kk];
    }
    float mx = acc[0];
#pragma unroll
    for (int r = 1; r < 10; ++r) mx = fmaxf(mx, acc[r]);
    for (int off = 1; off < 4; off <<= 1) mx = fmaxf(mx, __shfl_xor(mx, off, 4));
    float se = 0.f;
#pragma unroll
    for (int r = 0; r < 10; ++r) se += expf(acc[r] - mx);
    for (int off = 1; off < 4; off <<= 1) se += __shfl_xor(se, off, 4);
    float lse = logf(se);
#pragma unroll
    for (int r = 0; r < 10; ++r)
        out[(size_t)node * 40 + sub * 10 + r] = acc[r] - mx - lse;
}

// ---------------------------------------------------------------------------
extern "C" void kernel_launch(void* const* d_in, const int* in_sizes, int n_in,
                              void* d_out, int out_size, void* d_ws, size_t ws_size,
                              hipStream_t stream)
{
    const float* x = (const float*)d_in[0];
    const int* ei = (const int*)d_in[1];
    const int* src = ei;          // row 0
    const int* dst = ei + EE;     // row 1
    const float* W1[3] = {(const float*)d_in[2], (const float*)d_in[9],  (const float*)d_in[16]};
    const float* W2[3] = {(const float*)d_in[3], (const float*)d_in[10], (const float*)d_in[17]};
    const float* Wp[3] = {(const float*)d_in[4], (const float*)d_in[11], (const float*)d_in[18]};
    const float* g1[3] = {(const float*)d_in[5], (const float*)d_in[12], (const float*)d_in[19]};
    const float* b1[3] = {(const float*)d_in[6], (const float*)d_in[13], (const float*)d_in[20]};
    const float* g2[3] = {(const float*)d_in[7], (const float*)d_in[14], (const float*)d_in[21]};
    const float* b2[3] = {(const float*)d_in[8], (const float*)d_in[15], (const float*)d_in[22]};
    const float* gbn[2] = {(const float*)d_in[23], (const float*)d_in[25]};
    const float* bbn[2] = {(const float*)d_in[24], (const float*)d_in[26]};
    const float* Wm1 = (const float*)d_in[27];
    const float* bm1 = (const float*)d_in[28];
    const float* Wm2 = (const float*)d_in[29];
    const float* bm2 = (const float*)d_in[30];

    // workspace layout (floats): hbuf | sbuf | y1 | y2 | agg | small
    float* wsf  = (float*)d_ws;
    float* hbuf = wsf;                          // N*256 (layer input / H / hid, reused)
    float* sbuf = hbuf + (size_t)NN * DD;       // N*256 (JK sum)
    float* y1   = sbuf + (size_t)NN * DD;       // N*64
    float* y2   = y1 + (size_t)NN * 64;         // N*64
    float* agg  = y2 + (size_t)NN * 64;         // N*64
    float* sm   = agg + (size_t)NN * 64;
    float* ssum = sm;            // 256
    float* ssq  = sm + 256;      // 256
    float* a1p  = sm + 512;      // 64
    float* c1p  = sm + 576;      // 64
    float* a2p  = sm + 640;      // 64
    float* c2p  = sm + 704;      // 64
    float* W2f  = sm + 768;      // 4096
    float* b2f  = sm + 4864;     // 64
    float* ahp  = sm + 4928;     // 256
    float* chp  = sm + 5184;     // 256

    const dim3 blk(256);
    const float invN = 1.0f / NN;
    const int nb = (NN + 63) / 64;   // 469

    for (int l = 0; l < 3; ++l) {
        const float* xin = (l == 0) ? x : hbuf;
        int cin = (l == 0) ? IN_ : DD;

        hipMemsetAsync(ssum, 0, 512 * sizeof(float), stream);
        gemm_tile<<<dim3(nb, 1), blk, 0, stream>>>(xin, cin, W1[l], cin, nullptr,
                                                   y1, 64, NN, cin, 2, ssum, ssq);
        fold_bn<<<1, 64, 0, stream>>>(ssum, ssq, g1[l], b1[l], a1p, c1p, 64, invN);
        fold_w2<<<1, 64, 0, stream>>>(W2[l], a1p, c1p, W2f, b2f);

        hipMemsetAsync(ssum, 0, 512 * sizeof(float), stream);
        gemm_tile<<<dim3(nb, 1), blk, 0, stream>>>(y1, 64, W2f, 64, b2f,
                                                   y2, 64, NN, 64, 2, ssum, ssq);
        fold_bn<<<1, 64, 0, stream>>>(ssum, ssq, g2[l], b2[l], a2p, c2p, 64, invN);

        hipMemsetAsync(agg, 0, (size_t)NN * 64 * sizeof(float), stream);
        scatter_edges<<<(EE * 16 + 255) / 256, blk, 0, stream>>>(src, dst, y2, a2p, c2p, agg);

        bool st = (l < 2);
        if (st) hipMemsetAsync(ssum, 0, 512 * sizeof(float), stream);
        fog_biggemm<<<dim3(nb, 4), blk, 0, stream>>>(y1, a1p, c1p, agg, Wp[l], hbuf, NN,
                                                     st ? ssum : nullptr, st ? ssq : nullptr);
        if (st) {
            fold_bn<<<1, 256, 0, stream>>>(ssum, ssq, gbn[l], bbn[l], ahp, chp, 256, invN);
            bn_relu_jk<<<(NN * DD + 255) / 256, blk, 0, stream>>>(hbuf, ahp, chp, sbuf, hbuf, l == 0 ? 0 : 1);
        } else {
            bn_relu_jk<<<(NN * DD + 255) / 256, blk, 0, stream>>>(hbuf, nullptr, nullptr, sbuf, nullptr, 2);
        }
    }

    // MLP head: hid = relu(s @ Wm1.T + bm1) -> hbuf ; then logits + log_softmax
    gemm_tile<<<dim3(nb, 4), blk, 0, stream>>>(sbuf, DD, Wm1, DD, bm1,
                                               hbuf, DD, NN, DD, 1, nullptr, nullptr);
    mlp2_lsm<<<nb, blk, 0, stream>>>(hbuf, Wm2, bm2, (float*)d_out, NN);
}

// Round 2
// 3335.505 us; speedup vs baseline: 1.8708x; 1.8708x over previous
//
#include <hip/hip_runtime.h>
#include <math.h>

#define NN 30000
#define EE 960000
#define IN_ 128
#define DD 256
#define CC 40
#define EPS 1e-5f

typedef short bf8 __attribute__((ext_vector_type(8)));    // 8 bf16 (4 VGPRs)
typedef float f32x4 __attribute__((ext_vector_type(4)));

__device__ inline short f2bf(float x) {
    unsigned u = __float_as_uint(x);
    unsigned r = (u + 0x7fffu + ((u >> 16) & 1u)) >> 16;   // RNE
    return (short)r;
}

// ---------------------------------------------------------------------------
// Generic tiled f32 GEMM (small GEMMs + MLP head layer 1).
// ---------------------------------------------------------------------------
__global__ __launch_bounds__(256) void gemm_tile(
    const float* __restrict__ A, int lda,
    const float* __restrict__ W, int ldw,
    const float* __restrict__ bias,
    float* __restrict__ Cout, int ldc,
    int Nrows, int K, int act,
    float* __restrict__ ssum, float* __restrict__ ssq)
{
    __shared__ float At[32][68];   // [k][node]
    __shared__ float Wt[32][68];   // [k][col]
    const int t = threadIdx.x;
    const int nbase = blockIdx.x * 64;
    const int colbase = blockIdx.y * 64;
    const int tm = t & 15;
    const int td = t >> 4;
    float acc[4][4] = {};

    for (int kb = 0; kb < K; kb += 32) {
        __syncthreads();
#pragma unroll
        for (int rep = 0; rep < 8; ++rep) {
            int e = rep * 256 + t;
            int nl = e >> 5, kl = e & 31;
            int n = nbase + nl;
            float av = (n < Nrows) ? A[(size_t)n * lda + kb + kl] : 0.f;
            At[kl][nl] = av;
            Wt[kl][nl] = W[(size_t)(colbase + nl) * ldw + kb + kl];
        }
        __syncthreads();
#pragma unroll
        for (int k = 0; k < 32; ++k) {
            float4 a4 = *(const float4*)&At[k][tm * 4];
            float4 w4 = *(const float4*)&Wt[k][td * 4];
            float av[4] = {a4.x, a4.y, a4.z, a4.w};
            float wv[4] = {w4.x, w4.y, w4.z, w4.w};
#pragma unroll
            for (int m = 0; m < 4; ++m)
#pragma unroll
                for (int p = 0; p < 4; ++p)
                    acc[m][p] += av[m] * wv[p];
        }
    }

    float cs[4] = {}, cq[4] = {};
#pragma unroll
    for (int m = 0; m < 4; ++m) {
        int n = nbase + tm * 4 + m;
        if (n < Nrows) {
#pragma unroll
            for (int p = 0; p < 4; ++p) {
                float v = acc[m][p];
                if (bias) v += bias[colbase + td * 4 + p];
                if (act == 1) v = fmaxf(v, 0.f);
                else if (act == 2) v = (v > 0.f) ? v : 0.01f * v;
                Cout[(size_t)n * ldc + colbase + td * 4 + p] = v;
                cs[p] += v;
                cq[p] += v * v;
            }
        }
    }
    if (ssum) {
#pragma unroll
        for (int p = 0; p < 4; ++p) {
            float s1 = cs[p], s2 = cq[p];
            for (int off = 8; off >= 1; off >>= 1) {
                s1 += __shfl_down(s1, off, 16);
                s2 += __shfl_down(s2, off, 16);
            }
            if (tm == 0) {
                atomicAdd(&ssum[colbase + td * 4 + p], s1);
                atomicAdd(&ssq[colbase + td * 4 + p], s2);
            }
        }
    }
}

// ---------------------------------------------------------------------------
// Convert Wp (f32 [256][4096]) to bf16 pre-tiled in MFMA B-fragment order:
// frag (i, cb, jo): lane l holds Wp[cb*16 + (l&15)][i*64 + jo*32 + (l>>4)*8 + e]
// flat short8 index = ((i*16 + cb)*2 + jo)*64 + l
// ---------------------------------------------------------------------------
__global__ void conv_wp(const float* __restrict__ Wp, short* __restrict__ Wpb)
{
    int tid = blockIdx.x * 256 + threadIdx.x;   // 131072 threads
    int l = tid & 63;
    int r = tid >> 6;
    int jo = r & 1;
    int q = r >> 1;
    int cb = q & 15;
    int i = q >> 4;
    int col = cb * 16 + (l & 15);
    int k = i * 64 + jo * 32 + ((l >> 4) & 3) * 8;
    const float* src = Wp + (size_t)col * 4096 + k;
    bf8 v;
#pragma unroll
    for (int e = 0; e < 8; ++e) v[e] = f2bf(src[e]);
    ((bf8*)Wpb)[tid] = v;
}

// ---------------------------------------------------------------------------
// MFMA big GEMM: H[n,d] = sum_{i,j} xd[n,i]*ag[n,j] * Wp[d, i*64+j]
// Block: 256 thr = 4 waves; 64 nodes x 256 d-cols; wave w owns cols 64w..64w+63.
// K-loop: 64 steps (i); per step, A-tile [64 n][64 j] bf16 generated on the fly
// into chunk-major LDS At[8][64][8] (conflict-free b128 r/w); B-fragments
// loaded lane-contiguous from pre-tiled Wpb (L2-resident, no LDS).
// mfma_f32_16x16x32_bf16; C/D: col=lane&15, row=(lane>>4)*4+reg  [m89].
// ---------------------------------------------------------------------------
__global__ __launch_bounds__(256) void fog_mfma(
    const float* __restrict__ y1, const float* __restrict__ a1, const float* __restrict__ c1,
    const float* __restrict__ agg, const short* __restrict__ Wpb,
    float* __restrict__ H, int Nrows,
    float* __restrict__ ssum, float* __restrict__ ssq)
{
    __shared__ float xd_s[64][68];
    __shared__ short At[8][64][8];
    const int t = threadIdx.x;
    const int lane = t & 63;
    const int wid = t >> 6;
    const int nbase = blockIdx.x * 64;
    const int nl = t >> 2;       // local node this thread stages
    const int js = t & 3;        // j-16-group this thread owns

    float agr[16];
    {
        int n = nbase + nl;
        bool valid = n < Nrows;
        const float* yr = y1 + (size_t)n * 64 + js * 16;
        const float* ar = agg + (size_t)n * 64 + js * 16;
#pragma unroll
        for (int u = 0; u < 16; u += 4) {
            float4 yv = valid ? *(const float4*)(yr + u) : make_float4(0.f, 0.f, 0.f, 0.f);
            float4 av = valid ? *(const float4*)(ar + u) : make_float4(0.f, 0.f, 0.f, 0.f);
            int j0 = js * 16 + u;
            xd_s[nl][j0 + 0] = a1[j0 + 0] * yv.x + c1[j0 + 0];
            xd_s[nl][j0 + 1] = a1[j0 + 1] * yv.y + c1[j0 + 1];
            xd_s[nl][j0 + 2] = a1[j0 + 2] * yv.z + c1[j0 + 2];
            xd_s[nl][j0 + 3] = a1[j0 + 3] * yv.w + c1[j0 + 3];
            agr[u + 0] = av.x; agr[u + 1] = av.y; agr[u + 2] = av.z; agr[u + 3] = av.w;
        }
    }
    __syncthreads();

    f32x4 acc[4][4] = {};
    const bf8* wp8 = (const bf8*)Wpb;
    const int l15 = lane & 15, l4 = lane >> 4;

    for (int i = 0; i < 64; ++i) {
        // generate this step's A values (register-only; no LDS hazard yet)
        float xv = xd_s[nl][i];
        bf8 p0, p1;
#pragma unroll
        for (int e = 0; e < 8; ++e) {
            p0[e] = f2bf(xv * agr[e]);
            p1[e] = f2bf(xv * agr[8 + e]);
        }
        __syncthreads();            // all waves done reading At(i-1)
        *(bf8*)&At[js * 2 + 0][nl][0] = p0;
        *(bf8*)&At[js * 2 + 1][nl][0] = p1;
        __syncthreads();            // At(i) visible

        bf8 af[4][2], bfr[4][2];
#pragma unroll
        for (int mr = 0; mr < 4; ++mr)
#pragma unroll
            for (int jo = 0; jo < 2; ++jo)
                af[mr][jo] = *(const bf8*)&At[jo * 4 + l4][mr * 16 + l15][0];
#pragma unroll
        for (int nr = 0; nr < 4; ++nr) {
            int cb = wid * 4 + nr;
#pragma unroll
            for (int jo = 0; jo < 2; ++jo)
                bfr[nr][jo] = wp8[((i * 16 + cb) * 2 + jo) * 64 + lane];
        }
#pragma unroll
        for (int mr = 0; mr < 4; ++mr)
#pragma unroll
            for (int nr = 0; nr < 4; ++nr) {
                acc[mr][nr] = __builtin_amdgcn_mfma_f32_16x16x32_bf16(af[mr][0], bfr[nr][0], acc[mr][nr], 0, 0, 0);
                acc[mr][nr] = __builtin_amdgcn_mfma_f32_16x16x32_bf16(af[mr][1], bfr[nr][1], acc[mr][nr], 0, 0, 0);
            }
    }

    // epilogue: store H + per-column sum/sumsq
    float cs[4] = {}, cq[4] = {};
#pragma unroll
    for (int mr = 0; mr < 4; ++mr) {
#pragma unroll
        for (int r = 0; r < 4; ++r) {
            int n = nbase + mr * 16 + l4 * 4 + r;
            if (n < Nrows) {
#pragma unroll
                for (int nr = 0; nr < 4; ++nr) {
                    float v = acc[mr][nr][r];
                    H[(size_t)n * 256 + wid * 64 + nr * 16 + l15] = v;
                    cs[nr] += v;
                    cq[nr] += v * v;
                }
            }
        }
    }
    if (ssum) {
#pragma unroll
        for (int nr = 0; nr < 4; ++nr) {
            float s1 = cs[nr], s2 = cq[nr];
            s1 += __shfl_down(s1, 32);
            s2 += __shfl_down(s2, 32);
            s1 += __shfl_down(s1, 16);
            s2 += __shfl_down(s2, 16);
            if (l4 == 0) {
                atomicAdd(&ssum[wid * 64 + nr * 16 + l15], s1);
                atomicAdd(&ssq[wid * 64 + nr * 16 + l15], s2);
            }
        }
    }
}

// ---------------------------------------------------------------------------
// Edge scatter: agg[dst_e, :] += a2*y2[src_e, :] + c2
// ---------------------------------------------------------------------------
__global__ void scatter_edges(const int* __restrict__ src, const int* __restrict__ dst,
                              const float* __restrict__ y2,
                              const float* __restrict__ a2, const float* __restrict__ c2,
                              float* __restrict__ agg)
{
    long long idx = (long long)blockIdx.x * blockDim.x + threadIdx.x;
    if (idx >= (long long)EE * 16) return;
    int e = (int)(idx >> 4);
    int q = (int)(idx & 15);
    int s = src[e], d = dst[e];
    float4 v = *(const float4*)&y2[(size_t)s * 64 + q * 4];
    float4 a4 = *(const float4*)&a2[q * 4];
    float4 c4 = *(const float4*)&c2[q * 4];
    atomicAdd(&agg[(size_t)d * 64 + q * 4 + 0], a4.x * v.x + c4.x);
    atomicAdd(&agg[(size_t)d * 64 + q * 4 + 1], a4.y * v.y + c4.y);
    atomicAdd(&agg[(size_t)d * 64 + q * 4 + 2], a4.z * v.z + c4.z);
    atomicAdd(&agg[(size_t)d * 64 + q * 4 + 3], a4.w * v.w + c4.w);
}

// ---------------------------------------------------------------------------
__global__ void fold_bn(const float* __restrict__ ssum, const float* __restrict__ ssq,
                        const float* __restrict__ g, const float* __restrict__ b,
                        float* __restrict__ a, float* __restrict__ c, int len, float invN)
{
    int i = blockIdx.x * blockDim.x + threadIdx.x;
    if (i < len) {
        float m = ssum[i] * invN;
        float v = ssq[i] * invN - m * m;
        float s = g[i] * rsqrtf(v + EPS);
        a[i] = s;
        c[i] = b[i] - m * s;
    }
}

__global__ void fold_w2(const float* __restrict__ W2, const float* __restrict__ a1,
                        const float* __restrict__ c1,
                        float* __restrict__ W2f, float* __restrict__ b2f)
{
    int j = threadIdx.x;   // 64 threads
    float bb = 0.f;
    for (int i = 0; i < 64; ++i) {
        float w = W2[j * 64 + i];
        W2f[j * 64 + i] = w * a1[i];
        bb += w * c1[i];
    }
    b2f[j] = bb;
}

// ---------------------------------------------------------------------------
__global__ void bn_relu_jk(const float* __restrict__ Hh,
                           const float* __restrict__ ah, const float* __restrict__ ch,
                           float* __restrict__ s, float* __restrict__ xbuf, int mode)
{
    long long idx = (long long)blockIdx.x * blockDim.x + threadIdx.x;
    if (idx >= (long long)NN * DD) return;
    int dcol = (int)(idx & 255);
    float v = Hh[idx];
    if (mode < 2) {
        v = ah[dcol] * v + ch[dcol];
        v = fmaxf(v, 0.f);
        xbuf[idx] = v;
        s[idx] = (mode == 0) ? v : s[idx] + v;
    } else {
        s[idx] += v;
    }
}

// ---------------------------------------------------------------------------
__global__ __launch_bounds__(256) void mlp2_lsm(const float* __restrict__ hid,
                                                const float* __restrict__ Wm2,
                                                const float* __restrict__ bm2,
                                                float* __restrict__ out, int Nrows)
{
    __shared__ float Wl[40][257];
    __shared__ float bl[40];
    const int t = threadIdx.x;
    for (int e = t; e < 40 * 256; e += 256) {
        int c = e >> 8, k = e & 255;
        Wl[c][k] = Wm2[e];
    }
    if (t < 40) bl[t] = bm2[t];
    __syncthreads();

    int node = blockIdx.x * 64 + (t >> 2);
    int sub = t & 3;
    if (node >= Nrows) return;

    float acc[10];
#pragma unroll
    for (int r = 0; r < 10; ++r) acc[r] = bl[sub * 10 + r];
    const float* hrow = &hid[(size_t)node * 256];
    for (int k = 0; k < 256; k += 4) {
        float4 h4 = *(const float4*)&hrow[k];
        float hv[4] = {h4.x, h4.y, h4.z, h4.w};
#pragma unroll
        for (int kk = 0; kk < 4; ++kk)
#pragma unroll
            for (int r = 0; r < 10; ++r)
                acc[r] += hv[kk] * Wl[sub * 10 + r][k + kk];
    }
    float mx = acc[0];
#pragma unroll
    for (int r = 1; r < 10; ++r) mx = fmaxf(mx, acc[r]);
    for (int off = 1; off < 4; off <<= 1) mx = fmaxf(mx, __shfl_xor(mx, off, 4));
    float se = 0.f;
#pragma unroll
    for (int r = 0; r < 10; ++r) se += expf(acc[r] - mx);
    for (int off = 1; off < 4; off <<= 1) se += __shfl_xor(se, off, 4);
    float lse = logf(se);
#pragma unroll
    for (int r = 0; r < 10; ++r)
        out[(size_t)node * 40 + sub * 10 + r] = acc[r] - mx - lse;
}

// ---------------------------------------------------------------------------
extern "C" void kernel_launch(void* const* d_in, const int* in_sizes, int n_in,
                              void* d_out, int out_size, void* d_ws, size_t ws_size,
                              hipStream_t stream)
{
    const float* x = (const float*)d_in[0];
    const int* ei = (const int*)d_in[1];
    const int* src = ei;          // row 0
    const int* dst = ei + EE;     // row 1
    const float* W1[3] = {(const float*)d_in[2], (const float*)d_in[9],  (const float*)d_in[16]};
    const float* W2[3] = {(const float*)d_in[3], (const float*)d_in[10], (const float*)d_in[17]};
    const float* Wp[3] = {(const float*)d_in[4], (const float*)d_in[11], (const float*)d_in[18]};
    const float* g1[3] = {(const float*)d_in[5], (const float*)d_in[12], (const float*)d_in[19]};
    const float* b1[3] = {(const float*)d_in[6], (const float*)d_in[13], (const float*)d_in[20]};
    const float* g2[3] = {(const float*)d_in[7], (const float*)d_in[14], (const float*)d_in[21]};
    const float* b2[3] = {(const float*)d_in[8], (const float*)d_in[15], (const float*)d_in[22]};
    const float* gbn[2] = {(const float*)d_in[23], (const float*)d_in[25]};
    const float* bbn[2] = {(const float*)d_in[24], (const float*)d_in[26]};
    const float* Wm1 = (const float*)d_in[27];
    const float* bm1 = (const float*)d_in[28];
    const float* Wm2 = (const float*)d_in[29];
    const float* bm2 = (const float*)d_in[30];

    // workspace layout (floats): hbuf | sbuf | y1 | y2 | agg | small
    float* wsf  = (float*)d_ws;
    float* hbuf = wsf;                          // N*256
    float* sbuf = hbuf + (size_t)NN * DD;       // N*256
    float* y1   = sbuf + (size_t)NN * DD;       // N*64
    float* y2   = y1 + (size_t)NN * 64;         // N*64 (reused as Wpb after scatter)
    float* agg  = y2 + (size_t)NN * 64;         // N*64
    float* sm   = agg + (size_t)NN * 64;
    float* ssum = sm;            // 256
    float* ssq  = sm + 256;      // 256
    float* a1p  = sm + 512;      // 64
    float* c1p  = sm + 576;      // 64
    float* a2p  = sm + 640;      // 64
    float* c2p  = sm + 704;      // 64
    float* W2f  = sm + 768;      // 4096
    float* b2f  = sm + 4864;     // 64
    float* ahp  = sm + 4928;     // 256
    float* chp  = sm + 5184;     // 256

    const dim3 blk(256);
    const float invN = 1.0f / NN;
    const int nb = (NN + 63) / 64;   // 469

    for (int l = 0; l < 3; ++l) {
        const float* xin = (l == 0) ? x : hbuf;
        int cin = (l == 0) ? IN_ : DD;

        hipMemsetAsync(ssum, 0, 512 * sizeof(float), stream);
        gemm_tile<<<dim3(nb, 1), blk, 0, stream>>>(xin, cin, W1[l], cin, nullptr,
                                                   y1, 64, NN, cin, 2, ssum, ssq);
        fold_bn<<<1, 64, 0, stream>>>(ssum, ssq, g1[l], b1[l], a1p, c1p, 64, invN);
        fold_w2<<<1, 64, 0, stream>>>(W2[l], a1p, c1p, W2f, b2f);

        hipMemsetAsync(ssum, 0, 512 * sizeof(float), stream);
        gemm_tile<<<dim3(nb, 1), blk, 0, stream>>>(y1, 64, W2f, 64, b2f,
                                                   y2, 64, NN, 64, 2, ssum, ssq);
        fold_bn<<<1, 64, 0, stream>>>(ssum, ssq, g2[l], b2[l], a2p, c2p, 64, invN);

        hipMemsetAsync(agg, 0, (size_t)NN * 64 * sizeof(float), stream);
        scatter_edges<<<(EE * 16 + 255) / 256, blk, 0, stream>>>(src, dst, y2, a2p, c2p, agg);

        // y2 is dead after scatter -> reuse its space for the bf16 pre-tiled Wp
        short* Wpb = (short*)y2;
        conv_wp<<<512, blk, 0, stream>>>(Wp[l], Wpb);

        bool st = (l < 2);
        if (st) hipMemsetAsync(ssum, 0, 512 * sizeof(float), stream);
        fog_mfma<<<dim3(nb), blk, 0, stream>>>(y1, a1p, c1p, agg, Wpb, hbuf, NN,
                                               st ? ssum : nullptr, st ? ssq : nullptr);
        if (st) {
            fold_bn<<<1, 256, 0, stream>>>(ssum, ssq, gbn[l], bbn[l], ahp, chp, 256, invN);
            bn_relu_jk<<<(NN * DD + 255) / 256, blk, 0, stream>>>(hbuf, ahp, chp, sbuf, hbuf, l == 0 ? 0 : 1);
        } else {
            bn_relu_jk<<<(NN * DD + 255) / 256, blk, 0, stream>>>(hbuf, nullptr, nullptr, sbuf, nullptr, 2);
        }
    }

    // MLP head: hid = relu(s @ Wm1.T + bm1) -> hbuf ; then logits + log_softmax
    gemm_tile<<<dim3(nb, 4), blk, 0, stream>>>(sbuf, DD, Wm1, DD, bm1,
                                               hbuf, DD, NN, DD, 1, nullptr, nullptr);
    mlp2_lsm<<<nb, blk, 0, stream>>>(hbuf, Wm2, bm2, (float*)d_out, NN);
}

// Round 3
// 1096.313 us; speedup vs baseline: 5.6917x; 3.0425x over previous
//
#include <hip/hip_runtime.h>
#include <math.h>

#define NN 30000
#define EE 960000
#define IN_ 128
#define DD 256
#define CC 40
#define EPS 1e-5f

typedef short bf8 __attribute__((ext_vector_type(8)));    // 8 bf16 (4 VGPRs)
typedef float f32x4 __attribute__((ext_vector_type(4)));

__device__ inline short f2bf(float x) {
    unsigned u = __float_as_uint(x);
    unsigned r = (u + 0x7fffu + ((u >> 16) & 1u)) >> 16;   // RNE
    return (short)r;
}

// ---------------------------------------------------------------------------
// Generic tiled f32 GEMM (small GEMMs + MLP head layer 1).
// ---------------------------------------------------------------------------
__global__ __launch_bounds__(256) void gemm_tile(
    const float* __restrict__ A, int lda,
    const float* __restrict__ W, int ldw,
    const float* __restrict__ bias,
    float* __restrict__ Cout, int ldc,
    int Nrows, int K, int act,
    float* __restrict__ ssum, float* __restrict__ ssq)
{
    __shared__ float At[32][68];   // [k][node]
    __shared__ float Wt[32][68];   // [k][col]
    const int t = threadIdx.x;
    const int nbase = blockIdx.x * 64;
    const int colbase = blockIdx.y * 64;
    const int tm = t & 15;
    const int td = t >> 4;
    float acc[4][4] = {};

    for (int kb = 0; kb < K; kb += 32) {
        __syncthreads();
#pragma unroll
        for (int rep = 0; rep < 8; ++rep) {
            int e = rep * 256 + t;
            int nl = e >> 5, kl = e & 31;
            int n = nbase + nl;
            float av = (n < Nrows) ? A[(size_t)n * lda + kb + kl] : 0.f;
            At[kl][nl] = av;
            Wt[kl][nl] = W[(size_t)(colbase + nl) * ldw + kb + kl];
        }
        __syncthreads();
#pragma unroll
        for (int k = 0; k < 32; ++k) {
            float4 a4 = *(const float4*)&At[k][tm * 4];
            float4 w4 = *(const float4*)&Wt[k][td * 4];
            float av[4] = {a4.x, a4.y, a4.z, a4.w};
            float wv[4] = {w4.x, w4.y, w4.z, w4.w};
#pragma unroll
            for (int m = 0; m < 4; ++m)
#pragma unroll
                for (int p = 0; p < 4; ++p)
                    acc[m][p] += av[m] * wv[p];
        }
    }

    float cs[4] = {}, cq[4] = {};
#pragma unroll
    for (int m = 0; m < 4; ++m) {
        int n = nbase + tm * 4 + m;
        if (n < Nrows) {
#pragma unroll
            for (int p = 0; p < 4; ++p) {
                float v = acc[m][p];
                if (bias) v += bias[colbase + td * 4 + p];
                if (act == 1) v = fmaxf(v, 0.f);
                else if (act == 2) v = (v > 0.f) ? v : 0.01f * v;
                Cout[(size_t)n * ldc + colbase + td * 4 + p] = v;
                cs[p] += v;
                cq[p] += v * v;
            }
        }
    }
    if (ssum) {
#pragma unroll
        for (int p = 0; p < 4; ++p) {
            float s1 = cs[p], s2 = cq[p];
            for (int off = 8; off >= 1; off >>= 1) {
                s1 += __shfl_down(s1, off, 16);
                s2 += __shfl_down(s2, off, 16);
            }
            if (tm == 0) {
                atomicAdd(&ssum[colbase + td * 4 + p], s1);
                atomicAdd(&ssq[colbase + td * 4 + p], s2);
            }
        }
    }
}

// ---------------------------------------------------------------------------
// Convert Wp (f32 [256][4096]) to bf16 pre-tiled in MFMA B-fragment order.
// ---------------------------------------------------------------------------
__global__ void conv_wp(const float* __restrict__ Wp, short* __restrict__ Wpb)
{
    int tid = blockIdx.x * 256 + threadIdx.x;   // 131072 threads
    int l = tid & 63;
    int r = tid >> 6;
    int jo = r & 1;
    int q = r >> 1;
    int cb = q & 15;
    int i = q >> 4;
    int col = cb * 16 + (l & 15);
    int k = i * 64 + jo * 32 + ((l >> 4) & 3) * 8;
    const float* src = Wp + (size_t)col * 4096 + k;
    bf8 v;
#pragma unroll
    for (int e = 0; e < 8; ++e) v[e] = f2bf(src[e]);
    ((bf8*)Wpb)[tid] = v;
}

// ---------------------------------------------------------------------------
// MFMA big GEMM: H[n,d] = sum_{i,j} xd[n,i]*ag[n,j] * Wp[d, i*64+j]
// ---------------------------------------------------------------------------
__global__ __launch_bounds__(256) void fog_mfma(
    const float* __restrict__ y1, const float* __restrict__ a1, const float* __restrict__ c1,
    const float* __restrict__ agg, const short* __restrict__ Wpb,
    float* __restrict__ H, int Nrows,
    float* __restrict__ ssum, float* __restrict__ ssq)
{
    __shared__ float xd_s[64][68];
    __shared__ short At[8][64][8];
    const int t = threadIdx.x;
    const int lane = t & 63;
    const int wid = t >> 6;
    const int nbase = blockIdx.x * 64;
    const int nl = t >> 2;       // local node this thread stages
    const int js = t & 3;        // j-16-group this thread owns

    float agr[16];
    {
        int n = nbase + nl;
        bool valid = n < Nrows;
        const float* yr = y1 + (size_t)n * 64 + js * 16;
        const float* ar = agg + (size_t)n * 64 + js * 16;
#pragma unroll
        for (int u = 0; u < 16; u += 4) {
            float4 yv = valid ? *(const float4*)(yr + u) : make_float4(0.f, 0.f, 0.f, 0.f);
            float4 av = valid ? *(const float4*)(ar + u) : make_float4(0.f, 0.f, 0.f, 0.f);
            int j0 = js * 16 + u;
            xd_s[nl][j0 + 0] = a1[j0 + 0] * yv.x + c1[j0 + 0];
            xd_s[nl][j0 + 1] = a1[j0 + 1] * yv.y + c1[j0 + 1];
            xd_s[nl][j0 + 2] = a1[j0 + 2] * yv.z + c1[j0 + 2];
            xd_s[nl][j0 + 3] = a1[j0 + 3] * yv.w + c1[j0 + 3];
            agr[u + 0] = av.x; agr[u + 1] = av.y; agr[u + 2] = av.z; agr[u + 3] = av.w;
        }
    }
    __syncthreads();

    f32x4 acc[4][4] = {};
    const bf8* wp8 = (const bf8*)Wpb;
    const int l15 = lane & 15, l4 = lane >> 4;

    for (int i = 0; i < 64; ++i) {
        float xv = xd_s[nl][i];
        bf8 p0, p1;
#pragma unroll
        for (int e = 0; e < 8; ++e) {
            p0[e] = f2bf(xv * agr[e]);
            p1[e] = f2bf(xv * agr[8 + e]);
        }
        __syncthreads();            // all waves done reading At(i-1)
        *(bf8*)&At[js * 2 + 0][nl][0] = p0;
        *(bf8*)&At[js * 2 + 1][nl][0] = p1;
        __syncthreads();            // At(i) visible

        bf8 af[4][2], bfr[4][2];
#pragma unroll
        for (int mr = 0; mr < 4; ++mr)
#pragma unroll
            for (int jo = 0; jo < 2; ++jo)
                af[mr][jo] = *(const bf8*)&At[jo * 4 + l4][mr * 16 + l15][0];
#pragma unroll
        for (int nr = 0; nr < 4; ++nr) {
            int cb = wid * 4 + nr;
#pragma unroll
            for (int jo = 0; jo < 2; ++jo)
                bfr[nr][jo] = wp8[((i * 16 + cb) * 2 + jo) * 64 + lane];
        }
#pragma unroll
        for (int mr = 0; mr < 4; ++mr)
#pragma unroll
            for (int nr = 0; nr < 4; ++nr) {
                acc[mr][nr] = __builtin_amdgcn_mfma_f32_16x16x32_bf16(af[mr][0], bfr[nr][0], acc[mr][nr], 0, 0, 0);
                acc[mr][nr] = __builtin_amdgcn_mfma_f32_16x16x32_bf16(af[mr][1], bfr[nr][1], acc[mr][nr], 0, 0, 0);
            }
    }

    float cs[4] = {}, cq[4] = {};
#pragma unroll
    for (int mr = 0; mr < 4; ++mr) {
#pragma unroll
        for (int r = 0; r < 4; ++r) {
            int n = nbase + mr * 16 + l4 * 4 + r;
            if (n < Nrows) {
#pragma unroll
                for (int nr = 0; nr < 4; ++nr) {
                    float v = acc[mr][nr][r];
                    H[(size_t)n * 256 + wid * 64 + nr * 16 + l15] = v;
                    cs[nr] += v;
                    cq[nr] += v * v;
                }
            }
        }
    }
    if (ssum) {
#pragma unroll
        for (int nr = 0; nr < 4; ++nr) {
            float s1 = cs[nr], s2 = cq[nr];
            s1 += __shfl_down(s1, 32);
            s2 += __shfl_down(s2, 32);
            s1 += __shfl_down(s1, 16);
            s2 += __shfl_down(s2, 16);
            if (l4 == 0) {
                atomicAdd(&ssum[wid * 64 + nr * 16 + l15], s1);
                atomicAdd(&ssq[wid * 64 + nr * 16 + l15], s2);
            }
        }
    }
}

// ---------------------------------------------------------------------------
// CSR build: histogram of dst, prefix scan, fill src lists.
// ---------------------------------------------------------------------------
__global__ void hist_deg(const int* __restrict__ dst, int* __restrict__ deg)
{
    int e = blockIdx.x * 256 + threadIdx.x;
    if (e < EE) atomicAdd(&deg[dst[e]], 1);
}

__global__ void scan1(const int* __restrict__ deg, int* __restrict__ rowptr,
                      int* __restrict__ bsum)
{
    __shared__ int sh[256];
    int t = threadIdx.x;
    int i = blockIdx.x * 256 + t;
    int v = (i < NN) ? deg[i] : 0;
    sh[t] = v;
    __syncthreads();
    for (int off = 1; off < 256; off <<= 1) {
        int add = (t >= off) ? sh[t - off] : 0;
        __syncthreads();
        sh[t] += add;
        __syncthreads();
    }
    if (i < NN) rowptr[i] = sh[t] - v;          // exclusive
    if (t == 255) bsum[blockIdx.x] = sh[255];
}

__global__ void scan2(int* __restrict__ bsum, int* __restrict__ rowptr, int nb2)
{
    __shared__ int sh[256];
    int t = threadIdx.x;
    int v = (t < nb2) ? bsum[t] : 0;
    sh[t] = v;
    __syncthreads();
    for (int off = 1; off < 256; off <<= 1) {
        int add = (t >= off) ? sh[t - off] : 0;
        __syncthreads();
        sh[t] += add;
        __syncthreads();
    }
    if (t < nb2) bsum[t] = sh[t] - v;            // exclusive
    if (t == 0) rowptr[NN] = EE;
}

__global__ void scan3(int* __restrict__ rowptr, const int* __restrict__ bsum,
                      int* __restrict__ cursor)
{
    int i = blockIdx.x * 256 + threadIdx.x;
    if (i < NN) {
        int r = rowptr[i] + bsum[blockIdx.x];
        rowptr[i] = r;
        cursor[i] = r;
    }
}

__global__ void fill_csr(const int* __restrict__ src, const int* __restrict__ dst,
                         int* __restrict__ cursor, int* __restrict__ csr_src)
{
    int e = blockIdx.x * 256 + threadIdx.x;
    if (e < EE) {
        int p = atomicAdd(&cursor[dst[e]], 1);
        csr_src[p] = src[e];
    }
}

// ---------------------------------------------------------------------------
// Gather aggregation: agg[v] = a2 * (sum_{e: dst=v} y2[src_e]) + deg_v * c2
// 16 lanes per node; lane l owns float4 chunk l.
// ---------------------------------------------------------------------------
__global__ __launch_bounds__(256) void gather_agg(
    const int* __restrict__ rowptr, const int* __restrict__ csr_src,
    const float* __restrict__ y2,
    const float* __restrict__ a2, const float* __restrict__ c2,
    float* __restrict__ agg)
{
    int t = threadIdx.x;
    int g = t >> 4;
    int l = t & 15;
    int v = blockIdx.x * 16 + g;
    if (v >= NN) return;
    int beg = rowptr[v], end = rowptr[v + 1];
    float ax = 0.f, ay = 0.f, az = 0.f, aw = 0.f;
    for (int k = beg; k < end; ++k) {
        int s = csr_src[k];
        float4 val = *(const float4*)&y2[(size_t)s * 64 + l * 4];
        ax += val.x; ay += val.y; az += val.z; aw += val.w;
    }
    float dg = (float)(end - beg);
    float4 a4 = *(const float4*)&a2[l * 4];
    float4 c4 = *(const float4*)&c2[l * 4];
    float4 o;
    o.x = a4.x * ax + dg * c4.x;
    o.y = a4.y * ay + dg * c4.y;
    o.z = a4.z * az + dg * c4.z;
    o.w = a4.w * aw + dg * c4.w;
    *(float4*)&agg[(size_t)v * 64 + l * 4] = o;
}

// ---------------------------------------------------------------------------
__global__ void fold_bn(const float* __restrict__ ssum, const float* __restrict__ ssq,
                        const float* __restrict__ g, const float* __restrict__ b,
                        float* __restrict__ a, float* __restrict__ c, int len, float invN)
{
    int i = blockIdx.x * blockDim.x + threadIdx.x;
    if (i < len) {
        float m = ssum[i] * invN;
        float v = ssq[i] * invN - m * m;
        float s = g[i] * rsqrtf(v + EPS);
        a[i] = s;
        c[i] = b[i] - m * s;
    }
}

__global__ void fold_w2(const float* __restrict__ W2, const float* __restrict__ a1,
                        const float* __restrict__ c1,
                        float* __restrict__ W2f, float* __restrict__ b2f)
{
    int j = threadIdx.x;   // 64 threads
    float bb = 0.f;
    for (int i = 0; i < 64; ++i) {
        float w = W2[j * 64 + i];
        W2f[j * 64 + i] = w * a1[i];
        bb += w * c1[i];
    }
    b2f[j] = bb;
}

// ---------------------------------------------------------------------------
__global__ void bn_relu_jk(const float* __restrict__ Hh,
                           const float* __restrict__ ah, const float* __restrict__ ch,
                           float* __restrict__ s, float* __restrict__ xbuf, int mode)
{
    long long idx = (long long)blockIdx.x * blockDim.x + threadIdx.x;
    if (idx >= (long long)NN * DD) return;
    int dcol = (int)(idx & 255);
    float v = Hh[idx];
    if (mode < 2) {
        v = ah[dcol] * v + ch[dcol];
        v = fmaxf(v, 0.f);
        xbuf[idx] = v;
        s[idx] = (mode == 0) ? v : s[idx] + v;
    } else {
        s[idx] += v;
    }
}

// ---------------------------------------------------------------------------
__global__ __launch_bounds__(256) void mlp2_lsm(const float* __restrict__ hid,
                                                const float* __restrict__ Wm2,
                                                const float* __restrict__ bm2,
                                                float* __restrict__ out, int Nrows)
{
    __shared__ float Wl[40][257];
    __shared__ float bl[40];
    const int t = threadIdx.x;
    for (int e = t; e < 40 * 256; e += 256) {
        int c = e >> 8, k = e & 255;
        Wl[c][k] = Wm2[e];
    }
    if (t < 40) bl[t] = bm2[t];
    __syncthreads();

    int node = blockIdx.x * 64 + (t >> 2);
    int sub = t & 3;
    if (node >= Nrows) return;

    float acc[10];
#pragma unroll
    for (int r = 0; r < 10; ++r) acc[r] = bl[sub * 10 + r];
    const float* hrow = &hid[(size_t)node * 256];
    for (int k = 0; k < 256; k += 4) {
        float4 h4 = *(const float4*)&hrow[k];
        float hv[4] = {h4.x, h4.y, h4.z, h4.w};
#pragma unroll
        for (int kk = 0; kk < 4; ++kk)
#pragma unroll
            for (int r = 0; r < 10; ++r)
                acc[r] += hv[kk] * Wl[sub * 10 + r][k + kk];
    }
    float mx = acc[0];
#pragma unroll
    for (int r = 1; r < 10; ++r) mx = fmaxf(mx, acc[r]);
    for (int off = 1; off < 4; off <<= 1) mx = fmaxf(mx, __shfl_xor(mx, off, 4));
    float se = 0.f;
#pragma unroll
    for (int r = 0; r < 10; ++r) se += expf(acc[r] - mx);
    for (int off = 1; off < 4; off <<= 1) se += __shfl_xor(se, off, 4);
    float lse = logf(se);
#pragma unroll
    for (int r = 0; r < 10; ++r)
        out[(size_t)node * 40 + sub * 10 + r] = acc[r] - mx - lse;
}

// ---------------------------------------------------------------------------
extern "C" void kernel_launch(void* const* d_in, const int* in_sizes, int n_in,
                              void* d_out, int out_size, void* d_ws, size_t ws_size,
                              hipStream_t stream)
{
    const float* x = (const float*)d_in[0];
    const int* ei = (const int*)d_in[1];
    const int* src = ei;          // row 0
    const int* dst = ei + EE;     // row 1
    const float* W1[3] = {(const float*)d_in[2], (const float*)d_in[9],  (const float*)d_in[16]};
    const float* W2[3] = {(const float*)d_in[3], (const float*)d_in[10], (const float*)d_in[17]};
    const float* Wp[3] = {(const float*)d_in[4], (const float*)d_in[11], (const float*)d_in[18]};
    const float* g1[3] = {(const float*)d_in[5], (const float*)d_in[12], (const float*)d_in[19]};
    const float* b1[3] = {(const float*)d_in[6], (const float*)d_in[13], (const float*)d_in[20]};
    const float* g2[3] = {(const float*)d_in[7], (const float*)d_in[14], (const float*)d_in[21]};
    const float* b2[3] = {(const float*)d_in[8], (const float*)d_in[15], (const float*)d_in[22]};
    const float* gbn[2] = {(const float*)d_in[23], (const float*)d_in[25]};
    const float* bbn[2] = {(const float*)d_in[24], (const float*)d_in[26]};
    const float* Wm1 = (const float*)d_in[27];
    const float* bm1 = (const float*)d_in[28];
    const float* Wm2 = (const float*)d_in[29];
    const float* bm2 = (const float*)d_in[30];

    // workspace layout (floats): hbuf | sbuf | y1 | y2 | agg | small | csr(int)
    float* wsf  = (float*)d_ws;
    float* hbuf = wsf;                          // N*256
    float* sbuf = hbuf + (size_t)NN * DD;       // N*256
    float* y1   = sbuf + (size_t)NN * DD;       // N*64
    float* y2   = y1 + (size_t)NN * 64;         // N*64 (reused as Wpb after gather)
    float* agg  = y2 + (size_t)NN * 64;         // N*64
    float* sm   = agg + (size_t)NN * 64;
    float* ssum = sm;            // 256
    float* ssq  = sm + 256;      // 256
    float* a1p  = sm + 512;      // 64
    float* c1p  = sm + 576;      // 64
    float* a2p  = sm + 640;      // 64
    float* c2p  = sm + 704;      // 64
    float* W2f  = sm + 768;      // 4096
    float* b2f  = sm + 4864;     // 64
    float* ahp  = sm + 4928;     // 256
    float* chp  = sm + 5184;     // 256
    int* ibase   = (int*)(sm + 8192);
    int* deg     = ibase;                 // NN
    int* rowptr  = deg + NN;              // NN+1
    int* cursor  = rowptr + NN + 1;       // NN
    int* bsum    = cursor + NN;           // 256
    int* csr_src = bsum + 256;            // EE

    const dim3 blk(256);
    const float invN = 1.0f / NN;
    const int nb = (NN + 63) / 64;     // 469
    const int nb2 = (NN + 255) / 256;  // 118
    const int nbe = (EE + 255) / 256;  // 3750

    // ---- CSR build (once; reused by all 3 layers) ----
    hipMemsetAsync(deg, 0, NN * sizeof(int), stream);
    hist_deg<<<nbe, blk, 0, stream>>>(dst, deg);
    scan1<<<nb2, blk, 0, stream>>>(deg, rowptr, bsum);
    scan2<<<1, blk, 0, stream>>>(bsum, rowptr, nb2);
    scan3<<<nb2, blk, 0, stream>>>(rowptr, bsum, cursor);
    fill_csr<<<nbe, blk, 0, stream>>>(src, dst, cursor, csr_src);

    for (int l = 0; l < 3; ++l) {
        const float* xin = (l == 0) ? x : hbuf;
        int cin = (l == 0) ? IN_ : DD;

        hipMemsetAsync(ssum, 0, 512 * sizeof(float), stream);
        gemm_tile<<<dim3(nb, 1), blk, 0, stream>>>(xin, cin, W1[l], cin, nullptr,
                                                   y1, 64, NN, cin, 2, ssum, ssq);
        fold_bn<<<1, 64, 0, stream>>>(ssum, ssq, g1[l], b1[l], a1p, c1p, 64, invN);
        fold_w2<<<1, 64, 0, stream>>>(W2[l], a1p, c1p, W2f, b2f);

        hipMemsetAsync(ssum, 0, 512 * sizeof(float), stream);
        gemm_tile<<<dim3(nb, 1), blk, 0, stream>>>(y1, 64, W2f, 64, b2f,
                                                   y2, 64, NN, 64, 2, ssum, ssq);
        fold_bn<<<1, 64, 0, stream>>>(ssum, ssq, g2[l], b2[l], a2p, c2p, 64, invN);

        gather_agg<<<(NN + 15) / 16, blk, 0, stream>>>(rowptr, csr_src, y2, a2p, c2p, agg);

        // y2 is dead after gather -> reuse its space for the bf16 pre-tiled Wp
        short* Wpb = (short*)y2;
        conv_wp<<<512, blk, 0, stream>>>(Wp[l], Wpb);

        bool st = (l < 2);
        if (st) hipMemsetAsync(ssum, 0, 512 * sizeof(float), stream);
        fog_mfma<<<dim3(nb), blk, 0, stream>>>(y1, a1p, c1p, agg, Wpb, hbuf, NN,
                                               st ? ssum : nullptr, st ? ssq : nullptr);
        if (st) {
            fold_bn<<<1, 256, 0, stream>>>(ssum, ssq, gbn[l], bbn[l], ahp, chp, 256, invN);
            bn_relu_jk<<<(NN * DD + 255) / 256, blk, 0, stream>>>(hbuf, ahp, chp, sbuf, hbuf, l == 0 ? 0 : 1);
        } else {
            bn_relu_jk<<<(NN * DD + 255) / 256, blk, 0, stream>>>(hbuf, nullptr, nullptr, sbuf, nullptr, 2);
        }
    }

    // MLP head: hid = relu(s @ Wm1.T + bm1) -> hbuf ; then logits + log_softmax
    gemm_tile<<<dim3(nb, 4), blk, 0, stream>>>(sbuf, DD, Wm1, DD, bm1,
                                               hbuf, DD, NN, DD, 1, nullptr, nullptr);
    mlp2_lsm<<<nb, blk, 0, stream>>>(hbuf, Wm2, bm2, (float*)d_out, NN);
}

// Round 4
// 1040.838 us; speedup vs baseline: 5.9951x; 1.0533x over previous
//
#include <hip/hip_runtime.h>
#include <hip/hip_bf16.h>
#include <math.h>

#define NN 30000
#define EE 960000
#define IN_ 128
#define DD 256
#define CC 40
#define EPS 1e-5f

typedef short bf8 __attribute__((ext_vector_type(8)));    // 8 bf16 (4 VGPRs)
typedef float f32x4 __attribute__((ext_vector_type(4)));

__device__ inline short f2bf(float x) {
    unsigned u = __float_as_uint(x);
    unsigned r = (u + 0x7fffu + ((u >> 16) & 1u)) >> 16;   // RNE
    return (short)r;
}

// pack two floats -> one u32 of 2 bf16 (RNE), lo = first arg
__device__ inline unsigned pk2(float lo, float hi) {
    __hip_bfloat162 h = __float22bfloat162_rn(make_float2(lo, hi));
    return *reinterpret_cast<unsigned*>(&h);
}

// ---------------------------------------------------------------------------
// Generic tiled f32 GEMM (small GEMMs + MLP head layer 1).
// ---------------------------------------------------------------------------
__global__ __launch_bounds__(256) void gemm_tile(
    const float* __restrict__ A, int lda,
    const float* __restrict__ W, int ldw,
    const float* __restrict__ bias,
    float* __restrict__ Cout, int ldc,
    int Nrows, int K, int act,
    float* __restrict__ ssum, float* __restrict__ ssq)
{
    __shared__ float At[32][68];   // [k][node]
    __shared__ float Wt[32][68];   // [k][col]
    const int t = threadIdx.x;
    const int nbase = blockIdx.x * 64;
    const int colbase = blockIdx.y * 64;
    const int tm = t & 15;
    const int td = t >> 4;
    float acc[4][4] = {};

    for (int kb = 0; kb < K; kb += 32) {
        __syncthreads();
#pragma unroll
        for (int rep = 0; rep < 8; ++rep) {
            int e = rep * 256 + t;
            int nl = e >> 5, kl = e & 31;
            int n = nbase + nl;
            float av = (n < Nrows) ? A[(size_t)n * lda + kb + kl] : 0.f;
            At[kl][nl] = av;
            Wt[kl][nl] = W[(size_t)(colbase + nl) * ldw + kb + kl];
        }
        __syncthreads();
#pragma unroll
        for (int k = 0; k < 32; ++k) {
            float4 a4 = *(const float4*)&At[k][tm * 4];
            float4 w4 = *(const float4*)&Wt[k][td * 4];
            float av[4] = {a4.x, a4.y, a4.z, a4.w};
            float wv[4] = {w4.x, w4.y, w4.z, w4.w};
#pragma unroll
            for (int m = 0; m < 4; ++m)
#pragma unroll
                for (int p = 0; p < 4; ++p)
                    acc[m][p] += av[m] * wv[p];
        }
    }

    float cs[4] = {}, cq[4] = {};
#pragma unroll
    for (int m = 0; m < 4; ++m) {
        int n = nbase + tm * 4 + m;
        if (n < Nrows) {
#pragma unroll
            for (int p = 0; p < 4; ++p) {
                float v = acc[m][p];
                if (bias) v += bias[colbase + td * 4 + p];
                if (act == 1) v = fmaxf(v, 0.f);
                else if (act == 2) v = (v > 0.f) ? v : 0.01f * v;
                Cout[(size_t)n * ldc + colbase + td * 4 + p] = v;
                cs[p] += v;
                cq[p] += v * v;
            }
        }
    }
    if (ssum) {
#pragma unroll
        for (int p = 0; p < 4; ++p) {
            float s1 = cs[p], s2 = cq[p];
            for (int off = 8; off >= 1; off >>= 1) {
                s1 += __shfl_down(s1, off, 16);
                s2 += __shfl_down(s2, off, 16);
            }
            if (tm == 0) {
                atomicAdd(&ssum[colbase + td * 4 + p], s1);
                atomicAdd(&ssq[colbase + td * 4 + p], s2);
            }
        }
    }
}

// ---------------------------------------------------------------------------
// Convert Wp (f32 [256][4096]) to bf16 pre-tiled in MFMA B-fragment order.
// ---------------------------------------------------------------------------
__global__ void conv_wp(const float* __restrict__ Wp, short* __restrict__ Wpb)
{
    int tid = blockIdx.x * 256 + threadIdx.x;   // 131072 threads
    int l = tid & 63;
    int r = tid >> 6;
    int jo = r & 1;
    int q = r >> 1;
    int cb = q & 15;
    int i = q >> 4;
    int col = cb * 16 + (l & 15);
    int k = i * 64 + jo * 32 + ((l >> 4) & 3) * 8;
    const float* src = Wp + (size_t)col * 4096 + k;
    bf8 v;
#pragma unroll
    for (int e = 0; e < 8; ++e) v[e] = f2bf(src[e]);
    ((bf8*)Wpb)[tid] = v;
}

// ---------------------------------------------------------------------------
// MFMA big GEMM: H[n,d] = sum_{i,j} xd[n,i]*ag[n,j] * Wp[d, i*64+j]
// A-tile double-buffered (1 barrier/step); products packed via v_cvt_pk_bf16_f32.
// ---------------------------------------------------------------------------
__global__ __launch_bounds__(256) void fog_mfma(
    const float* __restrict__ y1, const float* __restrict__ a1, const float* __restrict__ c1,
    const float* __restrict__ agg, const short* __restrict__ Wpb,
    float* __restrict__ H, int Nrows,
    float* __restrict__ ssum, float* __restrict__ ssq)
{
    __shared__ float xd_s[64][68];
    __shared__ short At[2][8][64][8];
    const int t = threadIdx.x;
    const int lane = t & 63;
    const int wid = t >> 6;
    const int nbase = blockIdx.x * 64;
    const int nl = t >> 2;       // local node this thread stages
    const int js = t & 3;        // j-16-group this thread owns

    float agr[16];
    {
        int n = nbase + nl;
        bool valid = n < Nrows;
        const float* yr = y1 + (size_t)n * 64 + js * 16;
        const float* ar = agg + (size_t)n * 64 + js * 16;
#pragma unroll
        for (int u = 0; u < 16; u += 4) {
            float4 yv = valid ? *(const float4*)(yr + u) : make_float4(0.f, 0.f, 0.f, 0.f);
            float4 av = valid ? *(const float4*)(ar + u) : make_float4(0.f, 0.f, 0.f, 0.f);
            int j0 = js * 16 + u;
            xd_s[nl][j0 + 0] = a1[j0 + 0] * yv.x + c1[j0 + 0];
            xd_s[nl][j0 + 1] = a1[j0 + 1] * yv.y + c1[j0 + 1];
            xd_s[nl][j0 + 2] = a1[j0 + 2] * yv.z + c1[j0 + 2];
            xd_s[nl][j0 + 3] = a1[j0 + 3] * yv.w + c1[j0 + 3];
            agr[u + 0] = av.x; agr[u + 1] = av.y; agr[u + 2] = av.z; agr[u + 3] = av.w;
        }
    }
    __syncthreads();

    f32x4 acc[4][4] = {};
    const bf8* wp8 = (const bf8*)Wpb;
    const int l15 = lane & 15, l4 = lane >> 4;

    for (int i = 0; i < 64; ++i) {
        float xv = xd_s[nl][i];
        uint4 q0, q1;
        q0.x = pk2(xv * agr[0],  xv * agr[1]);
        q0.y = pk2(xv * agr[2],  xv * agr[3]);
        q0.z = pk2(xv * agr[4],  xv * agr[5]);
        q0.w = pk2(xv * agr[6],  xv * agr[7]);
        q1.x = pk2(xv * agr[8],  xv * agr[9]);
        q1.y = pk2(xv * agr[10], xv * agr[11]);
        q1.z = pk2(xv * agr[12], xv * agr[13]);
        q1.w = pk2(xv * agr[14], xv * agr[15]);
        short (*At_i)[64][8] = At[i & 1];
        *(uint4*)&At_i[js * 2 + 0][nl][0] = q0;
        *(uint4*)&At_i[js * 2 + 1][nl][0] = q1;
        __syncthreads();            // writes(i) visible; prior reads drained

        bf8 af[4][2], bfr[4][2];
#pragma unroll
        for (int mr = 0; mr < 4; ++mr)
#pragma unroll
            for (int jo = 0; jo < 2; ++jo)
                af[mr][jo] = *(const bf8*)&At_i[jo * 4 + l4][mr * 16 + l15][0];
#pragma unroll
        for (int nr = 0; nr < 4; ++nr) {
            int cb = wid * 4 + nr;
#pragma unroll
            for (int jo = 0; jo < 2; ++jo)
                bfr[nr][jo] = wp8[((i * 16 + cb) * 2 + jo) * 64 + lane];
        }
#pragma unroll
        for (int mr = 0; mr < 4; ++mr)
#pragma unroll
            for (int nr = 0; nr < 4; ++nr) {
                acc[mr][nr] = __builtin_amdgcn_mfma_f32_16x16x32_bf16(af[mr][0], bfr[nr][0], acc[mr][nr], 0, 0, 0);
                acc[mr][nr] = __builtin_amdgcn_mfma_f32_16x16x32_bf16(af[mr][1], bfr[nr][1], acc[mr][nr], 0, 0, 0);
            }
    }

    float cs[4] = {}, cq[4] = {};
#pragma unroll
    for (int mr = 0; mr < 4; ++mr) {
#pragma unroll
        for (int r = 0; r < 4; ++r) {
            int n = nbase + mr * 16 + l4 * 4 + r;
            if (n < Nrows) {
#pragma unroll
                for (int nr = 0; nr < 4; ++nr) {
                    float v = acc[mr][nr][r];
                    H[(size_t)n * 256 + wid * 64 + nr * 16 + l15] = v;
                    cs[nr] += v;
                    cq[nr] += v * v;
                }
            }
        }
    }
    if (ssum) {
#pragma unroll
        for (int nr = 0; nr < 4; ++nr) {
            float s1 = cs[nr], s2 = cq[nr];
            s1 += __shfl_down(s1, 32);
            s2 += __shfl_down(s2, 32);
            s1 += __shfl_down(s1, 16);
            s2 += __shfl_down(s2, 16);
            if (l4 == 0) {
                atomicAdd(&ssum[wid * 64 + nr * 16 + l15], s1);
                atomicAdd(&ssq[wid * 64 + nr * 16 + l15], s2);
            }
        }
    }
}

// ---------------------------------------------------------------------------
// CSR build: histogram of dst, prefix scan, fill src lists.
// ---------------------------------------------------------------------------
__global__ void hist_deg(const int* __restrict__ dst, int* __restrict__ deg)
{
    int e = blockIdx.x * 256 + threadIdx.x;
    if (e < EE) atomicAdd(&deg[dst[e]], 1);
}

__global__ void scan1(const int* __restrict__ deg, int* __restrict__ rowptr,
                      int* __restrict__ bsum)
{
    __shared__ int sh[256];
    int t = threadIdx.x;
    int i = blockIdx.x * 256 + t;
    int v = (i < NN) ? deg[i] : 0;
    sh[t] = v;
    __syncthreads();
    for (int off = 1; off < 256; off <<= 1) {
        int add = (t >= off) ? sh[t - off] : 0;
        __syncthreads();
        sh[t] += add;
        __syncthreads();
    }
    if (i < NN) rowptr[i] = sh[t] - v;          // exclusive
    if (t == 255) bsum[blockIdx.x] = sh[255];
}

__global__ void scan2(int* __restrict__ bsum, int* __restrict__ rowptr, int nb2)
{
    __shared__ int sh[256];
    int t = threadIdx.x;
    int v = (t < nb2) ? bsum[t] : 0;
    sh[t] = v;
    __syncthreads();
    for (int off = 1; off < 256; off <<= 1) {
        int add = (t >= off) ? sh[t - off] : 0;
        __syncthreads();
        sh[t] += add;
        __syncthreads();
    }
    if (t < nb2) bsum[t] = sh[t] - v;            // exclusive
    if (t == 0) rowptr[NN] = EE;
}

__global__ void scan3(int* __restrict__ rowptr, const int* __restrict__ bsum,
                      int* __restrict__ cursor)
{
    int i = blockIdx.x * 256 + threadIdx.x;
    if (i < NN) {
        int r = rowptr[i] + bsum[blockIdx.x];
        rowptr[i] = r;
        cursor[i] = r;
    }
}

__global__ void fill_csr(const int* __restrict__ src, const int* __restrict__ dst,
                         int* __restrict__ cursor, int* __restrict__ csr_src)
{
    int e = blockIdx.x * 256 + threadIdx.x;
    if (e < EE) {
        int p = atomicAdd(&cursor[dst[e]], 1);
        csr_src[p] = src[e];
    }
}

// ---------------------------------------------------------------------------
// Gather aggregation: agg[v] = a2 * (sum_{e: dst=v} y2[src_e]) + deg_v * c2
// 16 lanes per node; unroll x4 with prefetched indices (latency hiding).
// ---------------------------------------------------------------------------
__global__ __launch_bounds__(256) void gather_agg(
    const int* __restrict__ rowptr, const int* __restrict__ csr_src,
    const float* __restrict__ y2,
    const float* __restrict__ a2, const float* __restrict__ c2,
    float* __restrict__ agg)
{
    int t = threadIdx.x;
    int g = t >> 4;
    int l = t & 15;
    int v = blockIdx.x * 16 + g;
    if (v >= NN) return;
    int beg = rowptr[v], end = rowptr[v + 1];
    float ax0 = 0.f, ay0 = 0.f, az0 = 0.f, aw0 = 0.f;
    float ax1 = 0.f, ay1 = 0.f, az1 = 0.f, aw1 = 0.f;
    int k = beg;
    for (; k + 4 <= end; k += 4) {
        int s0 = csr_src[k + 0], s1 = csr_src[k + 1];
        int s2 = csr_src[k + 2], s3 = csr_src[k + 3];
        float4 v0 = *(const float4*)&y2[(size_t)s0 * 64 + l * 4];
        float4 v1 = *(const float4*)&y2[(size_t)s1 * 64 + l * 4];
        float4 v2 = *(const float4*)&y2[(size_t)s2 * 64 + l * 4];
        float4 v3 = *(const float4*)&y2[(size_t)s3 * 64 + l * 4];
        ax0 += v0.x + v1.x; ay0 += v0.y + v1.y; az0 += v0.z + v1.z; aw0 += v0.w + v1.w;
        ax1 += v2.x + v3.x; ay1 += v2.y + v3.y; az1 += v2.z + v3.z; aw1 += v2.w + v3.w;
    }
    for (; k < end; ++k) {
        int s = csr_src[k];
        float4 val = *(const float4*)&y2[(size_t)s * 64 + l * 4];
        ax0 += val.x; ay0 += val.y; az0 += val.z; aw0 += val.w;
    }
    float ax = ax0 + ax1, ay = ay0 + ay1, az = az0 + az1, aw = aw0 + aw1;
    float dg = (float)(end - beg);
    float4 a4 = *(const float4*)&a2[l * 4];
    float4 c4 = *(const float4*)&c2[l * 4];
    float4 o;
    o.x = a4.x * ax + dg * c4.x;
    o.y = a4.y * ay + dg * c4.y;
    o.z = a4.z * az + dg * c4.z;
    o.w = a4.w * aw + dg * c4.w;
    *(float4*)&agg[(size_t)v * 64 + l * 4] = o;
}

// ---------------------------------------------------------------------------
// fold BN1 (a1,c1) AND fold it into W2 in one launch (64 threads).
// ---------------------------------------------------------------------------
__global__ void fold_bn1_w2(const float* __restrict__ ssum, const float* __restrict__ ssq,
                            const float* __restrict__ g, const float* __restrict__ b,
                            float* __restrict__ a, float* __restrict__ c,
                            const float* __restrict__ W2,
                            float* __restrict__ W2f, float* __restrict__ b2f, float invN)
{
    __shared__ float as[64], cs[64];
    int j = threadIdx.x;   // 64 threads
    {
        float m = ssum[j] * invN;
        float v = ssq[j] * invN - m * m;
        float s = g[j] * rsqrtf(v + EPS);
        a[j] = s;
        c[j] = b[j] - m * s;
        as[j] = s;
        cs[j] = b[j] - m * s;
    }
    __syncthreads();
    float bb = 0.f;
    for (int i = 0; i < 64; ++i) {
        float w = W2[j * 64 + i];
        W2f[j * 64 + i] = w * as[i];
        bb += w * cs[i];
    }
    b2f[j] = bb;
}

__global__ void fold_bn(const float* __restrict__ ssum, const float* __restrict__ ssq,
                        const float* __restrict__ g, const float* __restrict__ b,
                        float* __restrict__ a, float* __restrict__ c, int len, float invN)
{
    int i = blockIdx.x * blockDim.x + threadIdx.x;
    if (i < len) {
        float m = ssum[i] * invN;
        float v = ssq[i] * invN - m * m;
        float s = g[i] * rsqrtf(v + EPS);
        a[i] = s;
        c[i] = b[i] - m * s;
    }
}

// ---------------------------------------------------------------------------
// JK epilogue, float4 vectorized.
// ---------------------------------------------------------------------------
__global__ void bn_relu_jk(const float4* __restrict__ Hh,
                           const float* __restrict__ ah, const float* __restrict__ ch,
                           float4* __restrict__ s, float4* __restrict__ xbuf, int mode)
{
    int idx = blockIdx.x * 256 + threadIdx.x;
    if (idx >= NN * DD / 4) return;
    int d0 = (idx & 63) * 4;
    float4 v = Hh[idx];
    if (mode < 2) {
        v.x = fmaxf(ah[d0 + 0] * v.x + ch[d0 + 0], 0.f);
        v.y = fmaxf(ah[d0 + 1] * v.y + ch[d0 + 1], 0.f);
        v.z = fmaxf(ah[d0 + 2] * v.z + ch[d0 + 2], 0.f);
        v.w = fmaxf(ah[d0 + 3] * v.w + ch[d0 + 3], 0.f);
        xbuf[idx] = v;
        if (mode == 0) s[idx] = v;
        else {
            float4 sv = s[idx];
            sv.x += v.x; sv.y += v.y; sv.z += v.z; sv.w += v.w;
            s[idx] = sv;
        }
    } else {
        float4 sv = s[idx];
        sv.x += v.x; sv.y += v.y; sv.z += v.z; sv.w += v.w;
        s[idx] = sv;
    }
}

// ---------------------------------------------------------------------------
__global__ __launch_bounds__(256) void mlp2_lsm(const float* __restrict__ hid,
                                                const float* __restrict__ Wm2,
                                                const float* __restrict__ bm2,
                                                float* __restrict__ out, int Nrows)
{
    __shared__ float Wl[40][257];
    __shared__ float bl[40];
    const int t = threadIdx.x;
    for (int e = t; e < 40 * 256; e += 256) {
        int c = e >> 8, k = e & 255;
        Wl[c][k] = Wm2[e];
    }
    if (t < 40) bl[t] = bm2[t];
    __syncthreads();

    int node = blockIdx.x * 64 + (t >> 2);
    int sub = t & 3;
    if (node >= Nrows) return;

    float acc[10];
#pragma unroll
    for (int r = 0; r < 10; ++r) acc[r] = bl[sub * 10 + r];
    const float* hrow = &hid[(size_t)node * 256];
    for (int k = 0; k < 256; k += 4) {
        float4 h4 = *(const float4*)&hrow[k];
        float hv[4] = {h4.x, h4.y, h4.z, h4.w};
#pragma unroll
        for (int kk = 0; kk < 4; ++kk)
#pragma unroll
            for (int r = 0; r < 10; ++r)
                acc[r] += hv[kk] * Wl[sub * 10 + r][k + kk];
    }
    float mx = acc[0];
#pragma unroll
    for (int r = 1; r < 10; ++r) mx = fmaxf(mx, acc[r]);
    for (int off = 1; off < 4; off <<= 1) mx = fmaxf(mx, __shfl_xor(mx, off, 4));
    float se = 0.f;
#pragma unroll
    for (int r = 0; r < 10; ++r) se += expf(acc[r] - mx);
    for (int off = 1; off < 4; off <<= 1) se += __shfl_xor(se, off, 4);
    float lse = logf(se);
#pragma unroll
    for (int r = 0; r < 10; ++r)
        out[(size_t)node * 40 + sub * 10 + r] = acc[r] - mx - lse;
}

// ---------------------------------------------------------------------------
extern "C" void kernel_launch(void* const* d_in, const int* in_sizes, int n_in,
                              void* d_out, int out_size, void* d_ws, size_t ws_size,
                              hipStream_t stream)
{
    const float* x = (const float*)d_in[0];
    const int* ei = (const int*)d_in[1];
    const int* src = ei;          // row 0
    const int* dst = ei + EE;     // row 1
    const float* W1[3] = {(const float*)d_in[2], (const float*)d_in[9],  (const float*)d_in[16]};
    const float* W2[3] = {(const float*)d_in[3], (const float*)d_in[10], (const float*)d_in[17]};
    const float* Wp[3] = {(const float*)d_in[4], (const float*)d_in[11], (const float*)d_in[18]};
    const float* g1[3] = {(const float*)d_in[5], (const float*)d_in[12], (const float*)d_in[19]};
    const float* b1[3] = {(const float*)d_in[6], (const float*)d_in[13], (const float*)d_in[20]};
    const float* g2[3] = {(const float*)d_in[7], (const float*)d_in[14], (const float*)d_in[21]};
    const float* b2[3] = {(const float*)d_in[8], (const float*)d_in[15], (const float*)d_in[22]};
    const float* gbn[2] = {(const float*)d_in[23], (const float*)d_in[25]};
    const float* bbn[2] = {(const float*)d_in[24], (const float*)d_in[26]};
    const float* Wm1 = (const float*)d_in[27];
    const float* bm1 = (const float*)d_in[28];
    const float* Wm2 = (const float*)d_in[29];
    const float* bm2 = (const float*)d_in[30];

    // workspace layout (floats): hbuf | sbuf | y1 | y2 | agg | small | csr(int)
    float* wsf  = (float*)d_ws;
    float* hbuf = wsf;                          // N*256
    float* sbuf = hbuf + (size_t)NN * DD;       // N*256
    float* y1   = sbuf + (size_t)NN * DD;       // N*64
    float* y2   = y1 + (size_t)NN * 64;         // N*64 (reused as Wpb after gather)
    float* agg  = y2 + (size_t)NN * 64;         // N*64
    float* sm   = agg + (size_t)NN * 64;
    float* ssum = sm;            // 256
    float* ssq  = sm + 256;      // 256
    float* a1p  = sm + 512;      // 64
    float* c1p  = sm + 576;      // 64
    float* a2p  = sm + 640;      // 64
    float* c2p  = sm + 704;      // 64
    float* W2f  = sm + 768;      // 4096
    float* b2f  = sm + 4864;     // 64
    float* ahp  = sm + 4928;     // 256
    float* chp  = sm + 5184;     // 256
    int* ibase   = (int*)(sm + 8192);
    int* deg     = ibase;                 // NN
    int* rowptr  = deg + NN;              // NN+1
    int* cursor  = rowptr + NN + 1;       // NN
    int* bsum    = cursor + NN;           // 256
    int* csr_src = bsum + 256;            // EE

    const dim3 blk(256);
    const float invN = 1.0f / NN;
    const int nb = (NN + 63) / 64;     // 469
    const int nb2 = (NN + 255) / 256;  // 118
    const int nbe = (EE + 255) / 256;  // 3750

    // ---- CSR build (once; reused by all 3 layers) ----
    hipMemsetAsync(deg, 0, NN * sizeof(int), stream);
    hist_deg<<<nbe, blk, 0, stream>>>(dst, deg);
    scan1<<<nb2, blk, 0, stream>>>(deg, rowptr, bsum);
    scan2<<<1, blk, 0, stream>>>(bsum, rowptr, nb2);
    scan3<<<nb2, blk, 0, stream>>>(rowptr, bsum, cursor);
    fill_csr<<<nbe, blk, 0, stream>>>(src, dst, cursor, csr_src);

    for (int l = 0; l < 3; ++l) {
        const float* xin = (l == 0) ? x : hbuf;
        int cin = (l == 0) ? IN_ : DD;

        hipMemsetAsync(ssum, 0, 512 * sizeof(float), stream);
        gemm_tile<<<dim3(nb, 1), blk, 0, stream>>>(xin, cin, W1[l], cin, nullptr,
                                                   y1, 64, NN, cin, 2, ssum, ssq);
        fold_bn1_w2<<<1, 64, 0, stream>>>(ssum, ssq, g1[l], b1[l], a1p, c1p,
                                          W2[l], W2f, b2f, invN);

        hipMemsetAsync(ssum, 0, 512 * sizeof(float), stream);
        gemm_tile<<<dim3(nb, 1), blk, 0, stream>>>(y1, 64, W2f, 64, b2f,
                                                   y2, 64, NN, 64, 2, ssum, ssq);
        fold_bn<<<1, 64, 0, stream>>>(ssum, ssq, g2[l], b2[l], a2p, c2p, 64, invN);

        gather_agg<<<(NN + 15) / 16, blk, 0, stream>>>(rowptr, csr_src, y2, a2p, c2p, agg);

        // y2 is dead after gather -> reuse its space for the bf16 pre-tiled Wp
        short* Wpb = (short*)y2;
        conv_wp<<<512, blk, 0, stream>>>(Wp[l], Wpb);

        bool st = (l < 2);
        if (st) hipMemsetAsync(ssum, 0, 512 * sizeof(float), stream);
        fog_mfma<<<dim3(nb), blk, 0, stream>>>(y1, a1p, c1p, agg, Wpb, hbuf, NN,
                                               st ? ssum : nullptr, st ? ssq : nullptr);
        if (st) {
            fold_bn<<<1, 256, 0, stream>>>(ssum, ssq, gbn[l], bbn[l], ahp, chp, 256, invN);
            bn_relu_jk<<<(NN * DD / 4 + 255) / 256, blk, 0, stream>>>(
                (const float4*)hbuf, ahp, chp, (float4*)sbuf, (float4*)hbuf, l == 0 ? 0 : 1);
        } else {
            bn_relu_jk<<<(NN * DD / 4 + 255) / 256, blk, 0, stream>>>(
                (const float4*)hbuf, nullptr, nullptr, (float4*)sbuf, nullptr, 2);
        }
    }

    // MLP head: hid = relu(s @ Wm1.T + bm1) -> hbuf ; then logits + log_softmax
    gemm_tile<<<dim3(nb, 4), blk, 0, stream>>>(sbuf, DD, Wm1, DD, bm1,
                                               hbuf, DD, NN, DD, 1, nullptr, nullptr);
    mlp2_lsm<<<nb, blk, 0, stream>>>(hbuf, Wm2, bm2, (float*)d_out, NN);
}

// Round 5
// 1017.682 us; speedup vs baseline: 6.1315x; 1.0228x over previous
//
#include <hip/hip_runtime.h>
#include <hip/hip_bf16.h>
#include <math.h>

#define NN 30000
#define EE 960000
#define IN_ 128
#define DD 256
#define CC 40
#define EPS 1e-5f

typedef short bf8 __attribute__((ext_vector_type(8)));    // 8 bf16 (4 VGPRs)
typedef float f32x4 __attribute__((ext_vector_type(4)));

__device__ inline short f2bf(float x) {
    unsigned u = __float_as_uint(x);
    unsigned r = (u + 0x7fffu + ((u >> 16) & 1u)) >> 16;   // RNE
    return (short)r;
}

// pack two floats -> one u32 of 2 bf16 (RNE), lo = first arg
__device__ inline unsigned pk2(float lo, float hi) {
    __hip_bfloat162 h = __float22bfloat162_rn(make_float2(lo, hi));
    return *reinterpret_cast<unsigned*>(&h);
}

// ---------------------------------------------------------------------------
// Generic tiled f32 GEMM (small GEMMs + MLP head layer 1).
// ---------------------------------------------------------------------------
__global__ __launch_bounds__(256) void gemm_tile(
    const float* __restrict__ A, int lda,
    const float* __restrict__ W, int ldw,
    const float* __restrict__ bias,
    float* __restrict__ Cout, int ldc,
    int Nrows, int K, int act,
    float* __restrict__ ssum, float* __restrict__ ssq)
{
    __shared__ float At[32][68];   // [k][node]
    __shared__ float Wt[32][68];   // [k][col]
    const int t = threadIdx.x;
    const int nbase = blockIdx.x * 64;
    const int colbase = blockIdx.y * 64;
    const int tm = t & 15;
    const int td = t >> 4;
    float acc[4][4] = {};

    for (int kb = 0; kb < K; kb += 32) {
        __syncthreads();
#pragma unroll
        for (int rep = 0; rep < 8; ++rep) {
            int e = rep * 256 + t;
            int nl = e >> 5, kl = e & 31;
            int n = nbase + nl;
            float av = (n < Nrows) ? A[(size_t)n * lda + kb + kl] : 0.f;
            At[kl][nl] = av;
            Wt[kl][nl] = W[(size_t)(colbase + nl) * ldw + kb + kl];
        }
        __syncthreads();
#pragma unroll
        for (int k = 0; k < 32; ++k) {
            float4 a4 = *(const float4*)&At[k][tm * 4];
            float4 w4 = *(const float4*)&Wt[k][td * 4];
            float av[4] = {a4.x, a4.y, a4.z, a4.w};
            float wv[4] = {w4.x, w4.y, w4.z, w4.w};
#pragma unroll
            for (int m = 0; m < 4; ++m)
#pragma unroll
                for (int p = 0; p < 4; ++p)
                    acc[m][p] += av[m] * wv[p];
        }
    }

    float cs[4] = {}, cq[4] = {};
#pragma unroll
    for (int m = 0; m < 4; ++m) {
        int n = nbase + tm * 4 + m;
        if (n < Nrows) {
#pragma unroll
            for (int p = 0; p < 4; ++p) {
                float v = acc[m][p];
                if (bias) v += bias[colbase + td * 4 + p];
                if (act == 1) v = fmaxf(v, 0.f);
                else if (act == 2) v = (v > 0.f) ? v : 0.01f * v;
                Cout[(size_t)n * ldc + colbase + td * 4 + p] = v;
                cs[p] += v;
                cq[p] += v * v;
            }
        }
    }
    if (ssum) {
#pragma unroll
        for (int p = 0; p < 4; ++p) {
            float s1 = cs[p], s2 = cq[p];
            for (int off = 8; off >= 1; off >>= 1) {
                s1 += __shfl_down(s1, off, 16);
                s2 += __shfl_down(s2, off, 16);
            }
            if (tm == 0) {
                atomicAdd(&ssum[colbase + td * 4 + p], s1);
                atomicAdd(&ssq[colbase + td * 4 + p], s2);
            }
        }
    }
}

// ---------------------------------------------------------------------------
// Convert Wp (f32 [256][4096]) to bf16 pre-tiled in MFMA B-fragment order.
// ---------------------------------------------------------------------------
__global__ void conv_wp(const float* __restrict__ Wp, short* __restrict__ Wpb)
{
    int tid = blockIdx.x * 256 + threadIdx.x;   // 131072 threads
    int l = tid & 63;
    int r = tid >> 6;
    int jo = r & 1;
    int q = r >> 1;
    int cb = q & 15;
    int i = q >> 4;
    int col = cb * 16 + (l & 15);
    int k = i * 64 + jo * 32 + ((l >> 4) & 3) * 8;
    const float* src = Wp + (size_t)col * 4096 + k;
    bf8 v;
#pragma unroll
    for (int e = 0; e < 8; ++e) v[e] = f2bf(src[e]);
    ((bf8*)Wpb)[tid] = v;
}

// ---------------------------------------------------------------------------
// MFMA big GEMM v3: H[n,d] = sum_{i,j} xd[n,i]*ag[n,j] * Wp[d, i*64+j]
// 512 thr = 8 waves; block = 64 nodes x 256 cols; wave w: rows 32*(w&1)..+31,
// cols 64*(w>>1)..+63. A-tile XOR-swizzled (node^chunk) -> conflict-free r/w.
// B fragments ping-pong prefetched one step ahead (covered by MFMA+A-gen).
// One barrier per K-step.
// ---------------------------------------------------------------------------
#define FOG_STEP(I, BUF, BU, BP)                                              \
  {                                                                           \
    bf8 af[2][2];                                                             \
    _Pragma("unroll")                                                         \
    for (int m = 0; m < 2; ++m) {                                             \
      _Pragma("unroll")                                                       \
      for (int jo = 0; jo < 2; ++jo) {                                        \
        int c = jo * 4 + l4;                                                  \
        int n = (mrb + m) * 16 + l15;                                         \
        af[m][jo] = *(const bf8*)&At[BUF][c][n ^ (c & 7)][0];                 \
      }                                                                       \
    }                                                                         \
    int inext = ((I) < 63) ? (I) + 1 : 63;                                    \
    _Pragma("unroll")                                                         \
    for (int nr = 0; nr < 4; ++nr) {                                          \
      _Pragma("unroll")                                                       \
      for (int jo = 0; jo < 2; ++jo)                                          \
        BP[nr][jo] = wp8[((inext * 16 + cbb + nr) * 2 + jo) * 64 + lane];     \
    }                                                                         \
    _Pragma("unroll")                                                         \
    for (int m = 0; m < 2; ++m) {                                             \
      _Pragma("unroll")                                                       \
      for (int nr = 0; nr < 4; ++nr) {                                        \
        acc[m][nr] = __builtin_amdgcn_mfma_f32_16x16x32_bf16(af[m][0], BU[nr][0], acc[m][nr], 0, 0, 0); \
        acc[m][nr] = __builtin_amdgcn_mfma_f32_16x16x32_bf16(af[m][1], BU[nr][1], acc[m][nr], 0, 0, 0); \
      }                                                                       \
    }                                                                         \
    if ((I) < 63) {                                                           \
      float xv = xd_s[nl][(I) + 1];                                           \
      uint4 q;                                                                \
      q.x = pk2(xv * agr[0], xv * agr[1]);                                    \
      q.y = pk2(xv * agr[2], xv * agr[3]);                                    \
      q.z = pk2(xv * agr[4], xv * agr[5]);                                    \
      q.w = pk2(xv * agr[6], xv * agr[7]);                                    \
      *(uint4*)&At[(BUF) ^ 1][js][nl ^ js][0] = q;                            \
    }                                                                         \
    __syncthreads();                                                          \
  }

__global__ __launch_bounds__(512) void fog_mfma(
    const float* __restrict__ y1, const float* __restrict__ a1, const float* __restrict__ c1,
    const float* __restrict__ agg, const short* __restrict__ Wpb,
    float* __restrict__ H, int Nrows,
    float* __restrict__ ssum, float* __restrict__ ssq)
{
    __shared__ float xd_s[64][68];
    __shared__ __align__(16) short At[2][8][64][8];   // [buf][chunk][node^chunk][8 bf16]
    const int t = threadIdx.x;          // 0..511
    const int lane = t & 63;
    const int w = t >> 6;               // wave 0..7
    const int nbase = blockIdx.x * 64;
    const int nl = t >> 3;              // staging node 0..63
    const int js = t & 7;               // staging j-chunk 0..7
    const int l15 = lane & 15;
    const int l4 = (lane >> 4) & 3;
    const int mrb = (w & 1) * 2;        // row 16-block base: 0 or 2
    const int cbb = (w >> 1) * 4;       // col 16-block base: 0,4,8,12

    // stage xd (BN1-folded y1) into LDS; agg chunk into regs
    float agr[8];
    {
        int n = nbase + nl;
        bool valid = n < Nrows;
        const float* yr = y1 + (size_t)n * 64 + js * 8;
        const float* ar = agg + (size_t)n * 64 + js * 8;
#pragma unroll
        for (int u = 0; u < 8; u += 4) {
            float4 yv = valid ? *(const float4*)(yr + u) : make_float4(0.f, 0.f, 0.f, 0.f);
            float4 av = valid ? *(const float4*)(ar + u) : make_float4(0.f, 0.f, 0.f, 0.f);
            int j0 = js * 8 + u;
            xd_s[nl][j0 + 0] = a1[j0 + 0] * yv.x + c1[j0 + 0];
            xd_s[nl][j0 + 1] = a1[j0 + 1] * yv.y + c1[j0 + 1];
            xd_s[nl][j0 + 2] = a1[j0 + 2] * yv.z + c1[j0 + 2];
            xd_s[nl][j0 + 3] = a1[j0 + 3] * yv.w + c1[j0 + 3];
            agr[u + 0] = av.x; agr[u + 1] = av.y; agr[u + 2] = av.z; agr[u + 3] = av.w;
        }
    }
    __syncthreads();

    const bf8* wp8 = (const bf8*)Wpb;
    // gen A(0) -> buf0 ; load B(0) -> bA
    {
        float xv = xd_s[nl][0];
        uint4 q;
        q.x = pk2(xv * agr[0], xv * agr[1]);
        q.y = pk2(xv * agr[2], xv * agr[3]);
        q.z = pk2(xv * agr[4], xv * agr[5]);
        q.w = pk2(xv * agr[6], xv * agr[7]);
        *(uint4*)&At[0][js][nl ^ js][0] = q;
    }
    bf8 bA[4][2], bB[4][2];
#pragma unroll
    for (int nr = 0; nr < 4; ++nr)
#pragma unroll
        for (int jo = 0; jo < 2; ++jo)
            bA[nr][jo] = wp8[((cbb + nr) * 2 + jo) * 64 + lane];
    __syncthreads();

    f32x4 acc[2][4] = {};
    for (int i = 0; i < 64; i += 2) {
        FOG_STEP(i,     0, bA, bB);
        FOG_STEP(i + 1, 1, bB, bA);
    }

    // epilogue: store H + per-column sum/sumsq
    float cs[4] = {}, cq[4] = {};
#pragma unroll
    for (int m = 0; m < 2; ++m) {
#pragma unroll
        for (int r = 0; r < 4; ++r) {
            int n = nbase + (mrb + m) * 16 + l4 * 4 + r;
            if (n < Nrows) {
#pragma unroll
                for (int nr = 0; nr < 4; ++nr) {
                    float v = acc[m][nr][r];
                    H[(size_t)n * 256 + (cbb + nr) * 16 + l15] = v;
                    cs[nr] += v;
                    cq[nr] += v * v;
                }
            }
        }
    }
    if (ssum) {
#pragma unroll
        for (int nr = 0; nr < 4; ++nr) {
            float s1 = cs[nr], s2 = cq[nr];
            s1 += __shfl_down(s1, 32);
            s2 += __shfl_down(s2, 32);
            s1 += __shfl_down(s1, 16);
            s2 += __shfl_down(s2, 16);
            if (l4 == 0 && lane < 16) {
                atomicAdd(&ssum[(cbb + nr) * 16 + l15], s1);
                atomicAdd(&ssq[(cbb + nr) * 16 + l15], s2);
            }
        }
    }
}

// ---------------------------------------------------------------------------
// CSR build: histogram of dst, prefix scan, fill src lists.
// ---------------------------------------------------------------------------
__global__ void hist_deg(const int* __restrict__ dst, int* __restrict__ deg)
{
    int e = blockIdx.x * 256 + threadIdx.x;
    if (e < EE) atomicAdd(&deg[dst[e]], 1);
}

__global__ void scan1(const int* __restrict__ deg, int* __restrict__ rowptr,
                      int* __restrict__ bsum)
{
    __shared__ int sh[256];
    int t = threadIdx.x;
    int i = blockIdx.x * 256 + t;
    int v = (i < NN) ? deg[i] : 0;
    sh[t] = v;
    __syncthreads();
    for (int off = 1; off < 256; off <<= 1) {
        int add = (t >= off) ? sh[t - off] : 0;
        __syncthreads();
        sh[t] += add;
        __syncthreads();
    }
    if (i < NN) rowptr[i] = sh[t] - v;          // exclusive
    if (t == 255) bsum[blockIdx.x] = sh[255];
}

__global__ void scan2(int* __restrict__ bsum, int* __restrict__ rowptr, int nb2)
{
    __shared__ int sh[256];
    int t = threadIdx.x;
    int v = (t < nb2) ? bsum[t] : 0;
    sh[t] = v;
    __syncthreads();
    for (int off = 1; off < 256; off <<= 1) {
        int add = (t >= off) ? sh[t - off] : 0;
        __syncthreads();
        sh[t] += add;
        __syncthreads();
    }
    if (t < nb2) bsum[t] = sh[t] - v;            // exclusive
    if (t == 0) rowptr[NN] = EE;
}

__global__ void scan3(int* __restrict__ rowptr, const int* __restrict__ bsum,
                      int* __restrict__ cursor)
{
    int i = blockIdx.x * 256 + threadIdx.x;
    if (i < NN) {
        int r = rowptr[i] + bsum[blockIdx.x];
        rowptr[i] = r;
        cursor[i] = r;
    }
}

__global__ void fill_csr(const int* __restrict__ src, const int* __restrict__ dst,
                         int* __restrict__ cursor, int* __restrict__ csr_src)
{
    int e = blockIdx.x * 256 + threadIdx.x;
    if (e < EE) {
        int p = atomicAdd(&cursor[dst[e]], 1);
        csr_src[p] = src[e];
    }
}

// ---------------------------------------------------------------------------
// Gather aggregation: agg[v] = a2 * (sum_{e: dst=v} y2[src_e]) + deg_v * c2
// 16 lanes per node; unroll x4 with prefetched indices (latency hiding).
// ---------------------------------------------------------------------------
__global__ __launch_bounds__(256) void gather_agg(
    const int* __restrict__ rowptr, const int* __restrict__ csr_src,
    const float* __restrict__ y2,
    const float* __restrict__ a2, const float* __restrict__ c2,
    float* __restrict__ agg)
{
    int t = threadIdx.x;
    int g = t >> 4;
    int l = t & 15;
    int v = blockIdx.x * 16 + g;
    if (v >= NN) return;
    int beg = rowptr[v], end = rowptr[v + 1];
    float ax0 = 0.f, ay0 = 0.f, az0 = 0.f, aw0 = 0.f;
    float ax1 = 0.f, ay1 = 0.f, az1 = 0.f, aw1 = 0.f;
    int k = beg;
    for (; k + 4 <= end; k += 4) {
        int s0 = csr_src[k + 0], s1 = csr_src[k + 1];
        int s2 = csr_src[k + 2], s3 = csr_src[k + 3];
        float4 v0 = *(const float4*)&y2[(size_t)s0 * 64 + l * 4];
        float4 v1 = *(const float4*)&y2[(size_t)s1 * 64 + l * 4];
        float4 v2 = *(const float4*)&y2[(size_t)s2 * 64 + l * 4];
        float4 v3 = *(const float4*)&y2[(size_t)s3 * 64 + l * 4];
        ax0 += v0.x + v1.x; ay0 += v0.y + v1.y; az0 += v0.z + v1.z; aw0 += v0.w + v1.w;
        ax1 += v2.x + v3.x; ay1 += v2.y + v3.y; az1 += v2.z + v3.z; aw1 += v2.w + v3.w;
    }
    for (; k < end; ++k) {
        int s = csr_src[k];
        float4 val = *(const float4*)&y2[(size_t)s * 64 + l * 4];
        ax0 += val.x; ay0 += val.y; az0 += val.z; aw0 += val.w;
    }
    float ax = ax0 + ax1, ay = ay0 + ay1, az = az0 + az1, aw = aw0 + aw1;
    float dg = (float)(end - beg);
    float4 a4 = *(const float4*)&a2[l * 4];
    float4 c4 = *(const float4*)&c2[l * 4];
    float4 o;
    o.x = a4.x * ax + dg * c4.x;
    o.y = a4.y * ay + dg * c4.y;
    o.z = a4.z * az + dg * c4.z;
    o.w = a4.w * aw + dg * c4.w;
    *(float4*)&agg[(size_t)v * 64 + l * 4] = o;
}

// ---------------------------------------------------------------------------
// fold BN1 (a1,c1) AND fold it into W2 in one launch (64 threads).
// ---------------------------------------------------------------------------
__global__ void fold_bn1_w2(const float* __restrict__ ssum, const float* __restrict__ ssq,
                            const float* __restrict__ g, const float* __restrict__ b,
                            float* __restrict__ a, float* __restrict__ c,
                            const float* __restrict__ W2,
                            float* __restrict__ W2f, float* __restrict__ b2f, float invN)
{
    __shared__ float as[64], cs[64];
    int j = threadIdx.x;   // 64 threads
    {
        float m = ssum[j] * invN;
        float v = ssq[j] * invN - m * m;
        float s = g[j] * rsqrtf(v + EPS);
        a[j] = s;
        c[j] = b[j] - m * s;
        as[j] = s;
        cs[j] = b[j] - m * s;
    }
    __syncthreads();
    float bb = 0.f;
    for (int i = 0; i < 64; ++i) {
        float w = W2[j * 64 + i];
        W2f[j * 64 + i] = w * as[i];
        bb += w * cs[i];
    }
    b2f[j] = bb;
}

__global__ void fold_bn(const float* __restrict__ ssum, const float* __restrict__ ssq,
                        const float* __restrict__ g, const float* __restrict__ b,
                        float* __restrict__ a, float* __restrict__ c, int len, float invN)
{
    int i = blockIdx.x * blockDim.x + threadIdx.x;
    if (i < len) {
        float m = ssum[i] * invN;
        float v = ssq[i] * invN - m * m;
        float s = g[i] * rsqrtf(v + EPS);
        a[i] = s;
        c[i] = b[i] - m * s;
    }
}

// ---------------------------------------------------------------------------
// JK epilogue, float4 vectorized.
// ---------------------------------------------------------------------------
__global__ void bn_relu_jk(const float4* __restrict__ Hh,
                           const float* __restrict__ ah, const float* __restrict__ ch,
                           float4* __restrict__ s, float4* __restrict__ xbuf, int mode)
{
    int idx = blockIdx.x * 256 + threadIdx.x;
    if (idx >= NN * DD / 4) return;
    int d0 = (idx & 63) * 4;
    float4 v = Hh[idx];
    if (mode < 2) {
        v.x = fmaxf(ah[d0 + 0] * v.x + ch[d0 + 0], 0.f);
        v.y = fmaxf(ah[d0 + 1] * v.y + ch[d0 + 1], 0.f);
        v.z = fmaxf(ah[d0 + 2] * v.z + ch[d0 + 2], 0.f);
        v.w = fmaxf(ah[d0 + 3] * v.w + ch[d0 + 3], 0.f);
        xbuf[idx] = v;
        if (mode == 0) s[idx] = v;
        else {
            float4 sv = s[idx];
            sv.x += v.x; sv.y += v.y; sv.z += v.z; sv.w += v.w;
            s[idx] = sv;
        }
    } else {
        float4 sv = s[idx];
        sv.x += v.x; sv.y += v.y; sv.z += v.z; sv.w += v.w;
        s[idx] = sv;
    }
}

// ---------------------------------------------------------------------------
__global__ __launch_bounds__(256) void mlp2_lsm(const float* __restrict__ hid,
                                                const float* __restrict__ Wm2,
                                                const float* __restrict__ bm2,
                                                float* __restrict__ out, int Nrows)
{
    __shared__ float Wl[40][257];
    __shared__ float bl[40];
    const int t = threadIdx.x;
    for (int e = t; e < 40 * 256; e += 256) {
        int c = e >> 8, k = e & 255;
        Wl[c][k] = Wm2[e];
    }
    if (t < 40) bl[t] = bm2[t];
    __syncthreads();

    int node = blockIdx.x * 64 + (t >> 2);
    int sub = t & 3;
    if (node >= Nrows) return;

    float acc[10];
#pragma unroll
    for (int r = 0; r < 10; ++r) acc[r] = bl[sub * 10 + r];
    const float* hrow = &hid[(size_t)node * 256];
    for (int k = 0; k < 256; k += 4) {
        float4 h4 = *(const float4*)&hrow[k];
        float hv[4] = {h4.x, h4.y, h4.z, h4.w};
#pragma unroll
        for (int kk = 0; kk < 4; ++kk)
#pragma unroll
            for (int r = 0; r < 10; ++r)
                acc[r] += hv[kk] * Wl[sub * 10 + r][k + kk];
    }
    float mx = acc[0];
#pragma unroll
    for (int r = 1; r < 10; ++r) mx = fmaxf(mx, acc[r]);
    for (int off = 1; off < 4; off <<= 1) mx = fmaxf(mx, __shfl_xor(mx, off, 4));
    float se = 0.f;
#pragma unroll
    for (int r = 0; r < 10; ++r) se += expf(acc[r] - mx);
    for (int off = 1; off < 4; off <<= 1) se += __shfl_xor(se, off, 4);
    float lse = logf(se);
#pragma unroll
    for (int r = 0; r < 10; ++r)
        out[(size_t)node * 40 + sub * 10 + r] = acc[r] - mx - lse;
}

// ---------------------------------------------------------------------------
extern "C" void kernel_launch(void* const* d_in, const int* in_sizes, int n_in,
                              void* d_out, int out_size, void* d_ws, size_t ws_size,
                              hipStream_t stream)
{
    const float* x = (const float*)d_in[0];
    const int* ei = (const int*)d_in[1];
    const int* src = ei;          // row 0
    const int* dst = ei + EE;     // row 1
    const float* W1[3] = {(const float*)d_in[2], (const float*)d_in[9],  (const float*)d_in[16]};
    const float* W2[3] = {(const float*)d_in[3], (const float*)d_in[10], (const float*)d_in[17]};
    const float* Wp[3] = {(const float*)d_in[4], (const float*)d_in[11], (const float*)d_in[18]};
    const float* g1[3] = {(const float*)d_in[5], (const float*)d_in[12], (const float*)d_in[19]};
    const float* b1[3] = {(const float*)d_in[6], (const float*)d_in[13], (const float*)d_in[20]};
    const float* g2[3] = {(const float*)d_in[7], (const float*)d_in[14], (const float*)d_in[21]};
    const float* b2[3] = {(const float*)d_in[8], (const float*)d_in[15], (const float*)d_in[22]};
    const float* gbn[2] = {(const float*)d_in[23], (const float*)d_in[25]};
    const float* bbn[2] = {(const float*)d_in[24], (const float*)d_in[26]};
    const float* Wm1 = (const float*)d_in[27];
    const float* bm1 = (const float*)d_in[28];
    const float* Wm2 = (const float*)d_in[29];
    const float* bm2 = (const float*)d_in[30];

    // workspace layout (floats): hbuf | sbuf | y1 | y2 | agg | small | csr(int)
    float* wsf  = (float*)d_ws;
    float* hbuf = wsf;                          // N*256
    float* sbuf = hbuf + (size_t)NN * DD;       // N*256
    float* y1   = sbuf + (size_t)NN * DD;       // N*64
    float* y2   = y1 + (size_t)NN * 64;         // N*64 (reused as Wpb after gather)
    float* agg  = y2 + (size_t)NN * 64;         // N*64
    float* sm   = agg + (size_t)NN * 64;
    float* ssum = sm;            // 256
    float* ssq  = sm + 256;      // 256
    float* a1p  = sm + 512;      // 64
    float* c1p  = sm + 576;      // 64
    float* a2p  = sm + 640;      // 64
    float* c2p  = sm + 704;      // 64
    float* W2f  = sm + 768;      // 4096
    float* b2f  = sm + 4864;     // 64
    float* ahp  = sm + 4928;     // 256
    float* chp  = sm + 5184;     // 256
    int* ibase   = (int*)(sm + 8192);
    int* deg     = ibase;                 // NN
    int* rowptr  = deg + NN;              // NN+1
    int* cursor  = rowptr + NN + 1;       // NN
    int* bsum    = cursor + NN;           // 256
    int* csr_src = bsum + 256;            // EE

    const dim3 blk(256);
    const float invN = 1.0f / NN;
    const int nb = (NN + 63) / 64;     // 469
    const int nb2 = (NN + 255) / 256;  // 118
    const int nbe = (EE + 255) / 256;  // 3750

    // ---- CSR build (once; reused by all 3 layers) ----
    hipMemsetAsync(deg, 0, NN * sizeof(int), stream);
    hist_deg<<<nbe, blk, 0, stream>>>(dst, deg);
    scan1<<<nb2, blk, 0, stream>>>(deg, rowptr, bsum);
    scan2<<<1, blk, 0, stream>>>(bsum, rowptr, nb2);
    scan3<<<nb2, blk, 0, stream>>>(rowptr, bsum, cursor);
    fill_csr<<<nbe, blk, 0, stream>>>(src, dst, cursor, csr_src);

    for (int l = 0; l < 3; ++l) {
        const float* xin = (l == 0) ? x : hbuf;
        int cin = (l == 0) ? IN_ : DD;

        hipMemsetAsync(ssum, 0, 512 * sizeof(float), stream);
        gemm_tile<<<dim3(nb, 1), blk, 0, stream>>>(xin, cin, W1[l], cin, nullptr,
                                                   y1, 64, NN, cin, 2, ssum, ssq);
        fold_bn1_w2<<<1, 64, 0, stream>>>(ssum, ssq, g1[l], b1[l], a1p, c1p,
                                          W2[l], W2f, b2f, invN);

        hipMemsetAsync(ssum, 0, 512 * sizeof(float), stream);
        gemm_tile<<<dim3(nb, 1), blk, 0, stream>>>(y1, 64, W2f, 64, b2f,
                                                   y2, 64, NN, 64, 2, ssum, ssq);
        fold_bn<<<1, 64, 0, stream>>>(ssum, ssq, g2[l], b2[l], a2p, c2p, 64, invN);

        gather_agg<<<(NN + 15) / 16, blk, 0, stream>>>(rowptr, csr_src, y2, a2p, c2p, agg);

        // y2 is dead after gather -> reuse its space for the bf16 pre-tiled Wp
        short* Wpb = (short*)y2;
        conv_wp<<<512, blk, 0, stream>>>(Wp[l], Wpb);

        bool st = (l < 2);
        if (st) hipMemsetAsync(ssum, 0, 512 * sizeof(float), stream);
        fog_mfma<<<dim3(nb), dim3(512), 0, stream>>>(y1, a1p, c1p, agg, Wpb, hbuf, NN,
                                                     st ? ssum : nullptr, st ? ssq : nullptr);
        if (st) {
            fold_bn<<<1, 256, 0, stream>>>(ssum, ssq, gbn[l], bbn[l], ahp, chp, 256, invN);
            bn_relu_jk<<<(NN * DD / 4 + 255) / 256, blk, 0, stream>>>(
                (const float4*)hbuf, ahp, chp, (float4*)sbuf, (float4*)hbuf, l == 0 ? 0 : 1);
        } else {
            bn_relu_jk<<<(NN * DD / 4 + 255) / 256, blk, 0, stream>>>(
                (const float4*)hbuf, nullptr, nullptr, (float4*)sbuf, nullptr, 2);
        }
    }

    // MLP head: hid = relu(s @ Wm1.T + bm1) -> hbuf ; then logits + log_softmax
    gemm_tile<<<dim3(nb, 4), blk, 0, stream>>>(sbuf, DD, Wm1, DD, bm1,
                                               hbuf, DD, NN, DD, 1, nullptr, nullptr);
    mlp2_lsm<<<nb, blk, 0, stream>>>(hbuf, Wm2, bm2, (float*)d_out, NN);
}

// Round 6
// 952.091 us; speedup vs baseline: 6.5539x; 1.0689x over previous
//
#include <hip/hip_runtime.h>
#include <hip/hip_bf16.h>
#include <math.h>

#define NN 30000
#define EE 960000
#define IN_ 128
#define DD 256
#define CC 40
#define EPS 1e-5f

typedef short bf8 __attribute__((ext_vector_type(8)));    // 8 bf16 (4 VGPRs)
typedef float f32x4 __attribute__((ext_vector_type(4)));

__device__ inline short f2bf(float x) {
    unsigned u = __float_as_uint(x);
    unsigned r = (u + 0x7fffu + ((u >> 16) & 1u)) >> 16;   // RNE
    return (short)r;
}

// pack two floats -> one u32 of 2 bf16 (RNE), lo = first arg
__device__ inline unsigned pk2(float lo, float hi) {
    __hip_bfloat162 h = __float22bfloat162_rn(make_float2(lo, hi));
    return *reinterpret_cast<unsigned*>(&h);
}

// ---------------------------------------------------------------------------
// Generic tiled f32 GEMM (small GEMMs y1/y2).
// ---------------------------------------------------------------------------
__global__ __launch_bounds__(256) void gemm_tile(
    const float* __restrict__ A, int lda,
    const float* __restrict__ W, int ldw,
    const float* __restrict__ bias,
    float* __restrict__ Cout, int ldc,
    int Nrows, int K, int act,
    float* __restrict__ ssum, float* __restrict__ ssq)
{
    __shared__ float At[32][68];   // [k][node]
    __shared__ float Wt[32][68];   // [k][col]
    const int t = threadIdx.x;
    const int nbase = blockIdx.x * 64;
    const int colbase = blockIdx.y * 64;
    const int tm = t & 15;
    const int td = t >> 4;
    float acc[4][4] = {};

    for (int kb = 0; kb < K; kb += 32) {
        __syncthreads();
#pragma unroll
        for (int rep = 0; rep < 8; ++rep) {
            int e = rep * 256 + t;
            int nl = e >> 5, kl = e & 31;
            int n = nbase + nl;
            float av = (n < Nrows) ? A[(size_t)n * lda + kb + kl] : 0.f;
            At[kl][nl] = av;
            Wt[kl][nl] = W[(size_t)(colbase + nl) * ldw + kb + kl];
        }
        __syncthreads();
#pragma unroll
        for (int k = 0; k < 32; ++k) {
            float4 a4 = *(const float4*)&At[k][tm * 4];
            float4 w4 = *(const float4*)&Wt[k][td * 4];
            float av[4] = {a4.x, a4.y, a4.z, a4.w};
            float wv[4] = {w4.x, w4.y, w4.z, w4.w};
#pragma unroll
            for (int m = 0; m < 4; ++m)
#pragma unroll
                for (int p = 0; p < 4; ++p)
                    acc[m][p] += av[m] * wv[p];
        }
    }

    float cs[4] = {}, cq[4] = {};
#pragma unroll
    for (int m = 0; m < 4; ++m) {
        int n = nbase + tm * 4 + m;
        if (n < Nrows) {
#pragma unroll
            for (int p = 0; p < 4; ++p) {
                float v = acc[m][p];
                if (bias) v += bias[colbase + td * 4 + p];
                if (act == 1) v = fmaxf(v, 0.f);
                else if (act == 2) v = (v > 0.f) ? v : 0.01f * v;
                Cout[(size_t)n * ldc + colbase + td * 4 + p] = v;
                cs[p] += v;
                cq[p] += v * v;
            }
        }
    }
    if (ssum) {
#pragma unroll
        for (int p = 0; p < 4; ++p) {
            float s1 = cs[p], s2 = cq[p];
            for (int off = 8; off >= 1; off >>= 1) {
                s1 += __shfl_down(s1, off, 16);
                s2 += __shfl_down(s2, off, 16);
            }
            if (tm == 0) {
                atomicAdd(&ssum[colbase + td * 4 + p], s1);
                atomicAdd(&ssq[colbase + td * 4 + p], s2);
            }
        }
    }
}

// ---------------------------------------------------------------------------
// Convert Wp (f32 [256][4096]) to bf16 pre-tiled in MFMA B-fragment order.
// ---------------------------------------------------------------------------
__global__ void conv_wp(const float* __restrict__ Wp, short* __restrict__ Wpb)
{
    int tid = blockIdx.x * 256 + threadIdx.x;   // 131072 threads
    int l = tid & 63;
    int r = tid >> 6;
    int jo = r & 1;
    int q = r >> 1;
    int cb = q & 15;
    int i = q >> 4;
    int col = cb * 16 + (l & 15);
    int k = i * 64 + jo * 32 + ((l >> 4) & 3) * 8;
    const float* src = Wp + (size_t)col * 4096 + k;
    bf8 v;
#pragma unroll
    for (int e = 0; e < 8; ++e) v[e] = f2bf(src[e]);
    ((bf8*)Wpb)[tid] = v;
}

// ---------------------------------------------------------------------------
// Convert Wm1 (f32 [256][256]) to bf16 hi/lo pre-tiled fragments.
// frag(ks 0..7, cb 0..15): lane l holds Wm1[cb*16+(l&15)][ks*32+(l>>4)*8+e]
// ---------------------------------------------------------------------------
__global__ void conv_wm1(const float* __restrict__ W,
                         short* __restrict__ Whi, short* __restrict__ Wlo)
{
    int tid = blockIdx.x * 256 + threadIdx.x;   // 8192 threads
    int l = tid & 63;
    int f = tid >> 6;
    int cb = f & 15;
    int ks = f >> 4;
    int col = cb * 16 + (l & 15);
    int k = ks * 32 + ((l >> 4) & 3) * 8;
    const float* src = W + (size_t)col * 256 + k;
    bf8 h, lo;
#pragma unroll
    for (int e = 0; e < 8; ++e) {
        float v = src[e];
        short hb = f2bf(v);
        float hf = __uint_as_float(((unsigned)(unsigned short)hb) << 16);
        h[e] = hb;
        lo[e] = f2bf(v - hf);
    }
    ((bf8*)Whi)[tid] = h;
    ((bf8*)Wlo)[tid] = lo;
}

// ---------------------------------------------------------------------------
// MFMA big GEMM v3 (+ fused JK-add for the last layer).
// 512 thr = 8 waves; block = 64 nodes x 256 cols.
// ---------------------------------------------------------------------------
#define FOG_STEP(I, BUF, BU, BP)                                              \
  {                                                                           \
    bf8 af[2][2];                                                             \
    _Pragma("unroll")                                                         \
    for (int m = 0; m < 2; ++m) {                                             \
      _Pragma("unroll")                                                       \
      for (int jo = 0; jo < 2; ++jo) {                                        \
        int c = jo * 4 + l4;                                                  \
        int n = (mrb + m) * 16 + l15;                                         \
        af[m][jo] = *(const bf8*)&At[BUF][c][n ^ (c & 7)][0];                 \
      }                                                                       \
    }                                                                         \
    int inext = ((I) < 63) ? (I) + 1 : 63;                                    \
    _Pragma("unroll")                                                         \
    for (int nr = 0; nr < 4; ++nr) {                                          \
      _Pragma("unroll")                                                       \
      for (int jo = 0; jo < 2; ++jo)                                          \
        BP[nr][jo] = wp8[((inext * 16 + cbb + nr) * 2 + jo) * 64 + lane];     \
    }                                                                         \
    _Pragma("unroll")                                                         \
    for (int m = 0; m < 2; ++m) {                                             \
      _Pragma("unroll")                                                       \
      for (int nr = 0; nr < 4; ++nr) {                                        \
        acc[m][nr] = __builtin_amdgcn_mfma_f32_16x16x32_bf16(af[m][0], BU[nr][0], acc[m][nr], 0, 0, 0); \
        acc[m][nr] = __builtin_amdgcn_mfma_f32_16x16x32_bf16(af[m][1], BU[nr][1], acc[m][nr], 0, 0, 0); \
      }                                                                       \
    }                                                                         \
    if ((I) < 63) {                                                           \
      float xv = xd_s[nl][(I) + 1];                                           \
      uint4 q;                                                                \
      q.x = pk2(xv * agr[0], xv * agr[1]);                                    \
      q.y = pk2(xv * agr[2], xv * agr[3]);                                    \
      q.z = pk2(xv * agr[4], xv * agr[5]);                                    \
      q.w = pk2(xv * agr[6], xv * agr[7]);                                    \
      *(uint4*)&At[(BUF) ^ 1][js][nl ^ js][0] = q;                            \
    }                                                                         \
    __syncthreads();                                                          \
  }

__global__ __launch_bounds__(512) void fog_mfma(
    const float* __restrict__ y1, const float* __restrict__ a1, const float* __restrict__ c1,
    const float* __restrict__ agg, const short* __restrict__ Wpb,
    float* __restrict__ H, int Nrows,
    float* __restrict__ ssum, float* __restrict__ ssq,
    float* __restrict__ sjk)
{
    __shared__ float xd_s[64][68];
    __shared__ __align__(16) short At[2][8][64][8];   // [buf][chunk][node^chunk][8 bf16]
    const int t = threadIdx.x;          // 0..511
    const int lane = t & 63;
    const int w = t >> 6;               // wave 0..7
    const int nbase = blockIdx.x * 64;
    const int nl = t >> 3;              // staging node 0..63
    const int js = t & 7;               // staging j-chunk 0..7
    const int l15 = lane & 15;
    const int l4 = (lane >> 4) & 3;
    const int mrb = (w & 1) * 2;        // row 16-block base: 0 or 2
    const int cbb = (w >> 1) * 4;       // col 16-block base: 0,4,8,12

    float agr[8];
    {
        int n = nbase + nl;
        bool valid = n < Nrows;
        const float* yr = y1 + (size_t)n * 64 + js * 8;
        const float* ar = agg + (size_t)n * 64 + js * 8;
#pragma unroll
        for (int u = 0; u < 8; u += 4) {
            float4 yv = valid ? *(const float4*)(yr + u) : make_float4(0.f, 0.f, 0.f, 0.f);
            float4 av = valid ? *(const float4*)(ar + u) : make_float4(0.f, 0.f, 0.f, 0.f);
            int j0 = js * 8 + u;
            xd_s[nl][j0 + 0] = a1[j0 + 0] * yv.x + c1[j0 + 0];
            xd_s[nl][j0 + 1] = a1[j0 + 1] * yv.y + c1[j0 + 1];
            xd_s[nl][j0 + 2] = a1[j0 + 2] * yv.z + c1[j0 + 2];
            xd_s[nl][j0 + 3] = a1[j0 + 3] * yv.w + c1[j0 + 3];
            agr[u + 0] = av.x; agr[u + 1] = av.y; agr[u + 2] = av.z; agr[u + 3] = av.w;
        }
    }
    __syncthreads();

    const bf8* wp8 = (const bf8*)Wpb;
    {
        float xv = xd_s[nl][0];
        uint4 q;
        q.x = pk2(xv * agr[0], xv * agr[1]);
        q.y = pk2(xv * agr[2], xv * agr[3]);
        q.z = pk2(xv * agr[4], xv * agr[5]);
        q.w = pk2(xv * agr[6], xv * agr[7]);
        *(uint4*)&At[0][js][nl ^ js][0] = q;
    }
    bf8 bA[4][2], bB[4][2];
#pragma unroll
    for (int nr = 0; nr < 4; ++nr)
#pragma unroll
        for (int jo = 0; jo < 2; ++jo)
            bA[nr][jo] = wp8[((cbb + nr) * 2 + jo) * 64 + lane];
    __syncthreads();

    f32x4 acc[2][4] = {};
    for (int i = 0; i < 64; i += 2) {
        FOG_STEP(i,     0, bA, bB);
        FOG_STEP(i + 1, 1, bB, bA);
    }

    if (ssum) {
        float cs[4] = {}, cq[4] = {};
#pragma unroll
        for (int m = 0; m < 2; ++m) {
#pragma unroll
            for (int r = 0; r < 4; ++r) {
                int n = nbase + (mrb + m) * 16 + l4 * 4 + r;
                if (n < Nrows) {
#pragma unroll
                    for (int nr = 0; nr < 4; ++nr) {
                        float v = acc[m][nr][r];
                        H[(size_t)n * 256 + (cbb + nr) * 16 + l15] = v;
                        cs[nr] += v;
                        cq[nr] += v * v;
                    }
                }
            }
        }
#pragma unroll
        for (int nr = 0; nr < 4; ++nr) {
            float s1 = cs[nr], s2 = cq[nr];
            s1 += __shfl_down(s1, 32);
            s2 += __shfl_down(s2, 32);
            s1 += __shfl_down(s1, 16);
            s2 += __shfl_down(s2, 16);
            if (l4 == 0 && lane < 16) {
                atomicAdd(&ssum[(cbb + nr) * 16 + l15], s1);
                atomicAdd(&ssq[(cbb + nr) * 16 + l15], s2);
            }
        }
    } else {
        // last layer: s += x3 fused (each (n,col) owned by exactly one thread)
#pragma unroll
        for (int m = 0; m < 2; ++m) {
#pragma unroll
            for (int r = 0; r < 4; ++r) {
                int n = nbase + (mrb + m) * 16 + l4 * 4 + r;
                if (n < Nrows) {
#pragma unroll
                    for (int nr = 0; nr < 4; ++nr) {
                        size_t idx = (size_t)n * 256 + (cbb + nr) * 16 + l15;
                        sjk[idx] += acc[m][nr][r];
                    }
                }
            }
        }
    }
}

// ---------------------------------------------------------------------------
// MLP head layer 1 via bf16x3 split MFMA (f32-equivalent precision).
// hid = relu(A @ Wm1.T + bm1); 512 thr = 8 waves; block = 64 rows x 256 cols.
// A-fragments loaded directly from global (perfect 128B segment coverage).
// ---------------------------------------------------------------------------
__global__ __launch_bounds__(512) void head_mfma(
    const float* __restrict__ A,
    const short* __restrict__ Whi, const short* __restrict__ Wlo,
    const float* __restrict__ bias,
    float* __restrict__ Out, int Nrows)
{
    const int t = threadIdx.x;
    const int lane = t & 63;
    const int w = t >> 6;
    const int nbase = blockIdx.x * 64;
    const int l15 = lane & 15, l4 = (lane >> 4) & 3;
    const int mrb = (w & 1) * 32;       // row base within tile: 0 or 32
    const int cbb = (w >> 1) * 4;       // col 16-block base: 0,4,8,12
    const bf8* whi = (const bf8*)Whi;
    const bf8* wlo = (const bf8*)Wlo;

    f32x4 acc[2][4] = {};
#pragma unroll
    for (int ks = 0; ks < 8; ++ks) {
        bf8 ah[2], al[2];
#pragma unroll
        for (int m = 0; m < 2; ++m) {
            int n = nbase + mrb + m * 16 + l15;
            float4 f0, f1;
            if (n < Nrows) {
                const float* p = &A[(size_t)n * 256 + ks * 32 + l4 * 8];
                f0 = *(const float4*)p;
                f1 = *(const float4*)(p + 4);
            } else {
                f0 = make_float4(0.f, 0.f, 0.f, 0.f);
                f1 = f0;
            }
            unsigned h0 = pk2(f0.x, f0.y), h1 = pk2(f0.z, f0.w);
            unsigned h2 = pk2(f1.x, f1.y), h3 = pk2(f1.z, f1.w);
            float e0 = f0.x - __uint_as_float(h0 << 16);
            float e1 = f0.y - __uint_as_float(h0 & 0xFFFF0000u);
            float e2 = f0.z - __uint_as_float(h1 << 16);
            float e3 = f0.w - __uint_as_float(h1 & 0xFFFF0000u);
            float e4 = f1.x - __uint_as_float(h2 << 16);
            float e5 = f1.y - __uint_as_float(h2 & 0xFFFF0000u);
            float e6 = f1.z - __uint_as_float(h3 << 16);
            float e7 = f1.w - __uint_as_float(h3 & 0xFFFF0000u);
            uint4 hu = make_uint4(h0, h1, h2, h3);
            uint4 lu = make_uint4(pk2(e0, e1), pk2(e2, e3), pk2(e4, e5), pk2(e6, e7));
            ah[m] = *(bf8*)&hu;
            al[m] = *(bf8*)&lu;
        }
        bf8 bh[4], bl[4];
#pragma unroll
        for (int nr = 0; nr < 4; ++nr) {
            int idx = (ks * 16 + cbb + nr) * 64 + lane;
            bh[nr] = whi[idx];
            bl[nr] = wlo[idx];
        }
#pragma unroll
        for (int m = 0; m < 2; ++m)
#pragma unroll
            for (int nr = 0; nr < 4; ++nr) {
                acc[m][nr] = __builtin_amdgcn_mfma_f32_16x16x32_bf16(ah[m], bh[nr], acc[m][nr], 0, 0, 0);
                acc[m][nr] = __builtin_amdgcn_mfma_f32_16x16x32_bf16(ah[m], bl[nr], acc[m][nr], 0, 0, 0);
                acc[m][nr] = __builtin_amdgcn_mfma_f32_16x16x32_bf16(al[m], bh[nr], acc[m][nr], 0, 0, 0);
            }
    }

#pragma unroll
    for (int m = 0; m < 2; ++m) {
#pragma unroll
        for (int r = 0; r < 4; ++r) {
            int n = nbase + mrb + m * 16 + l4 * 4 + r;
            if (n < Nrows) {
#pragma unroll
                for (int nr = 0; nr < 4; ++nr) {
                    int col = (cbb + nr) * 16 + l15;
                    float v = acc[m][nr][r] + bias[col];
                    Out[(size_t)n * 256 + col] = fmaxf(v, 0.f);
                }
            }
        }
    }
}

// ---------------------------------------------------------------------------
// CSR build: histogram of dst, prefix scan, fill src lists.
// ---------------------------------------------------------------------------
__global__ void hist_deg(const int* __restrict__ dst, int* __restrict__ deg)
{
    int e = blockIdx.x * 256 + threadIdx.x;
    if (e < EE) atomicAdd(&deg[dst[e]], 1);
}

__global__ void scan1(const int* __restrict__ deg, int* __restrict__ rowptr,
                      int* __restrict__ bsum)
{
    __shared__ int sh[256];
    int t = threadIdx.x;
    int i = blockIdx.x * 256 + t;
    int v = (i < NN) ? deg[i] : 0;
    sh[t] = v;
    __syncthreads();
    for (int off = 1; off < 256; off <<= 1) {
        int add = (t >= off) ? sh[t - off] : 0;
        __syncthreads();
        sh[t] += add;
        __syncthreads();
    }
    if (i < NN) rowptr[i] = sh[t] - v;          // exclusive
    if (t == 255) bsum[blockIdx.x] = sh[255];
}

__global__ void scan2(int* __restrict__ bsum, int* __restrict__ rowptr, int nb2)
{
    __shared__ int sh[256];
    int t = threadIdx.x;
    int v = (t < nb2) ? bsum[t] : 0;
    sh[t] = v;
    __syncthreads();
    for (int off = 1; off < 256; off <<= 1) {
        int add = (t >= off) ? sh[t - off] : 0;
        __syncthreads();
        sh[t] += add;
        __syncthreads();
    }
    if (t < nb2) bsum[t] = sh[t] - v;            // exclusive
    if (t == 0) rowptr[NN] = EE;
}

__global__ void scan3(int* __restrict__ rowptr, const int* __restrict__ bsum,
                      int* __restrict__ cursor)
{
    int i = blockIdx.x * 256 + threadIdx.x;
    if (i < NN) {
        int r = rowptr[i] + bsum[blockIdx.x];
        rowptr[i] = r;
        cursor[i] = r;
    }
}

__global__ void fill_csr(const int* __restrict__ src, const int* __restrict__ dst,
                         int* __restrict__ cursor, int* __restrict__ csr_src)
{
    int e = blockIdx.x * 256 + threadIdx.x;
    if (e < EE) {
        int p = atomicAdd(&cursor[dst[e]], 1);
        csr_src[p] = src[e];
    }
}

// ---------------------------------------------------------------------------
// Gather aggregation: agg[v] = a2 * (sum_{e: dst=v} y2[src_e]) + deg_v * c2
// ---------------------------------------------------------------------------
__global__ __launch_bounds__(256) void gather_agg(
    const int* __restrict__ rowptr, const int* __restrict__ csr_src,
    const float* __restrict__ y2,
    const float* __restrict__ a2, const float* __restrict__ c2,
    float* __restrict__ agg)
{
    int t = threadIdx.x;
    int g = t >> 4;
    int l = t & 15;
    int v = blockIdx.x * 16 + g;
    if (v >= NN) return;
    int beg = rowptr[v], end = rowptr[v + 1];
    float ax0 = 0.f, ay0 = 0.f, az0 = 0.f, aw0 = 0.f;
    float ax1 = 0.f, ay1 = 0.f, az1 = 0.f, aw1 = 0.f;
    int k = beg;
    for (; k + 4 <= end; k += 4) {
        int s0 = csr_src[k + 0], s1 = csr_src[k + 1];
        int s2 = csr_src[k + 2], s3 = csr_src[k + 3];
        float4 v0 = *(const float4*)&y2[(size_t)s0 * 64 + l * 4];
        float4 v1 = *(const float4*)&y2[(size_t)s1 * 64 + l * 4];
        float4 v2 = *(const float4*)&y2[(size_t)s2 * 64 + l * 4];
        float4 v3 = *(const float4*)&y2[(size_t)s3 * 64 + l * 4];
        ax0 += v0.x + v1.x; ay0 += v0.y + v1.y; az0 += v0.z + v1.z; aw0 += v0.w + v1.w;
        ax1 += v2.x + v3.x; ay1 += v2.y + v3.y; az1 += v2.z + v3.z; aw1 += v2.w + v3.w;
    }
    for (; k < end; ++k) {
        int s = csr_src[k];
        float4 val = *(const float4*)&y2[(size_t)s * 64 + l * 4];
        ax0 += val.x; ay0 += val.y; az0 += val.z; aw0 += val.w;
    }
    float ax = ax0 + ax1, ay = ay0 + ay1, az = az0 + az1, aw = aw0 + aw1;
    float dg = (float)(end - beg);
    float4 a4 = *(const float4*)&a2[l * 4];
    float4 c4 = *(const float4*)&c2[l * 4];
    float4 o;
    o.x = a4.x * ax + dg * c4.x;
    o.y = a4.y * ay + dg * c4.y;
    o.z = a4.z * az + dg * c4.z;
    o.w = a4.w * aw + dg * c4.w;
    *(float4*)&agg[(size_t)v * 64 + l * 4] = o;
}

// ---------------------------------------------------------------------------
// fold BN1 (a1,c1) AND fold into W2; zeroes ssum/ssq[0..63] after reading.
// ---------------------------------------------------------------------------
__global__ void fold_bn1_w2(float* __restrict__ ssum, float* __restrict__ ssq,
                            const float* __restrict__ g, const float* __restrict__ b,
                            float* __restrict__ a, float* __restrict__ c,
                            const float* __restrict__ W2,
                            float* __restrict__ W2f, float* __restrict__ b2f, float invN)
{
    __shared__ float as[64], cs[64];
    int j = threadIdx.x;   // 64 threads
    {
        float m = ssum[j] * invN;
        float v = ssq[j] * invN - m * m;
        float s = g[j] * rsqrtf(v + EPS);
        a[j] = s;
        c[j] = b[j] - m * s;
        as[j] = s;
        cs[j] = b[j] - m * s;
        ssum[j] = 0.f;
        ssq[j] = 0.f;
    }
    __syncthreads();
    float bb = 0.f;
    for (int i = 0; i < 64; ++i) {
        float w = W2[j * 64 + i];
        W2f[j * 64 + i] = w * as[i];
        bb += w * cs[i];
    }
    b2f[j] = bb;
}

// fold BN; zeroes ssum/ssq[0..len) after reading.
__global__ void fold_bn(float* __restrict__ ssum, float* __restrict__ ssq,
                        const float* __restrict__ g, const float* __restrict__ b,
                        float* __restrict__ a, float* __restrict__ c, int len, float invN)
{
    int i = blockIdx.x * blockDim.x + threadIdx.x;
    if (i < len) {
        float m = ssum[i] * invN;
        float v = ssq[i] * invN - m * m;
        float s = g[i] * rsqrtf(v + EPS);
        a[i] = s;
        c[i] = b[i] - m * s;
        ssum[i] = 0.f;
        ssq[i] = 0.f;
    }
}

// ---------------------------------------------------------------------------
// JK epilogue (layers 0,1), float4 vectorized.
// ---------------------------------------------------------------------------
__global__ void bn_relu_jk(const float4* __restrict__ Hh,
                           const float* __restrict__ ah, const float* __restrict__ ch,
                           float4* __restrict__ s, float4* __restrict__ xbuf, int mode)
{
    int idx = blockIdx.x * 256 + threadIdx.x;
    if (idx >= NN * DD / 4) return;
    int d0 = (idx & 63) * 4;
    float4 v = Hh[idx];
    v.x = fmaxf(ah[d0 + 0] * v.x + ch[d0 + 0], 0.f);
    v.y = fmaxf(ah[d0 + 1] * v.y + ch[d0 + 1], 0.f);
    v.z = fmaxf(ah[d0 + 2] * v.z + ch[d0 + 2], 0.f);
    v.w = fmaxf(ah[d0 + 3] * v.w + ch[d0 + 3], 0.f);
    xbuf[idx] = v;
    if (mode == 0) s[idx] = v;
    else {
        float4 sv = s[idx];
        sv.x += v.x; sv.y += v.y; sv.z += v.z; sv.w += v.w;
        s[idx] = sv;
    }
}

// ---------------------------------------------------------------------------
__global__ __launch_bounds__(256) void mlp2_lsm(const float* __restrict__ hid,
                                                const float* __restrict__ Wm2,
                                                const float* __restrict__ bm2,
                                                float* __restrict__ out, int Nrows)
{
    __shared__ float Wl[40][257];
    __shared__ float bl[40];
    const int t = threadIdx.x;
    for (int e = t; e < 40 * 256; e += 256) {
        int c = e >> 8, k = e & 255;
        Wl[c][k] = Wm2[e];
    }
    if (t < 40) bl[t] = bm2[t];
    __syncthreads();

    int node = blockIdx.x * 64 + (t >> 2);
    int sub = t & 3;
    if (node >= Nrows) return;

    float acc[10];
#pragma unroll
    for (int r = 0; r < 10; ++r) acc[r] = bl[sub * 10 + r];
    const float* hrow = &hid[(size_t)node * 256];
    for (int k = 0; k < 256; k += 4) {
        float4 h4 = *(const float4*)&hrow[k];
        float hv[4] = {h4.x, h4.y, h4.z, h4.w};
#pragma unroll
        for (int kk = 0; kk < 4; ++kk)
#pragma unroll
            for (int r = 0; r < 10; ++r)
                acc[r] += hv[kk] * Wl[sub * 10 + r][k + kk];
    }
    float mx = acc[0];
#pragma unroll
    for (int r = 1; r < 10; ++r) mx = fmaxf(mx, acc[r]);
    for (int off = 1; off < 4; off <<= 1) mx = fmaxf(mx, __shfl_xor(mx, off, 4));
    float se = 0.f;
#pragma unroll
    for (int r = 0; r < 10; ++r) se += expf(acc[r] - mx);
    for (int off = 1; off < 4; off <<= 1) se += __shfl_xor(se, off, 4);
    float lse = logf(se);
#pragma unroll
    for (int r = 0; r < 10; ++r)
        out[(size_t)node * 40 + sub * 10 + r] = acc[r] - mx - lse;
}

// ---------------------------------------------------------------------------
extern "C" void kernel_launch(void* const* d_in, const int* in_sizes, int n_in,
                              void* d_out, int out_size, void* d_ws, size_t ws_size,
                              hipStream_t stream)
{
    const float* x = (const float*)d_in[0];
    const int* ei = (const int*)d_in[1];
    const int* src = ei;          // row 0
    const int* dst = ei + EE;     // row 1
    const float* W1[3] = {(const float*)d_in[2], (const float*)d_in[9],  (const float*)d_in[16]};
    const float* W2[3] = {(const float*)d_in[3], (const float*)d_in[10], (const float*)d_in[17]};
    const float* Wp[3] = {(const float*)d_in[4], (const float*)d_in[11], (const float*)d_in[18]};
    const float* g1[3] = {(const float*)d_in[5], (const float*)d_in[12], (const float*)d_in[19]};
    const float* b1[3] = {(const float*)d_in[6], (const float*)d_in[13], (const float*)d_in[20]};
    const float* g2[3] = {(const float*)d_in[7], (const float*)d_in[14], (const float*)d_in[21]};
    const float* b2[3] = {(const float*)d_in[8], (const float*)d_in[15], (const float*)d_in[22]};
    const float* gbn[2] = {(const float*)d_in[23], (const float*)d_in[25]};
    const float* bbn[2] = {(const float*)d_in[24], (const float*)d_in[26]};
    const float* Wm1 = (const float*)d_in[27];
    const float* bm1 = (const float*)d_in[28];
    const float* Wm2 = (const float*)d_in[29];
    const float* bm2 = (const float*)d_in[30];

    // workspace layout (floats): hbuf | sbuf | y1 | y2 | agg | small | csr(int) | wm1 frags
    float* wsf  = (float*)d_ws;
    float* hbuf = wsf;                          // N*256
    float* sbuf = hbuf + (size_t)NN * DD;       // N*256
    float* y1   = sbuf + (size_t)NN * DD;       // N*64
    float* y2   = y1 + (size_t)NN * 64;         // N*64 (reused as Wpb)
    float* agg  = y2 + (size_t)NN * 64;         // N*64
    float* sm   = agg + (size_t)NN * 64;
    float* ssum = sm;            // 256
    float* ssq  = sm + 256;      // 256
    float* a1p  = sm + 512;      // 64
    float* c1p  = sm + 576;      // 64
    float* a2p  = sm + 640;      // 64
    float* c2p  = sm + 704;      // 64
    float* W2f  = sm + 768;      // 4096
    float* b2f  = sm + 4864;     // 64
    float* ahp  = sm + 4928;     // 256
    float* chp  = sm + 5184;     // 256
    int* ibase   = (int*)(sm + 8192);
    int* deg     = ibase;                 // NN
    int* rowptr  = deg + NN;              // NN+1
    int* cursor  = rowptr + NN + 1;       // NN
    int* bsum    = cursor + NN;           // 256
    int* csr_src = bsum + 256;            // EE
    int  ioff    = ((NN * 3 + 1 + 256 + EE) + 7) & ~7;   // align 32B
    short* wm1h  = (short*)(ibase + ioff);     // 65536 shorts
    short* wm1l  = wm1h + 65536;               // 65536 shorts

    const dim3 blk(256);
    const float invN = 1.0f / NN;
    const int nb = (NN + 63) / 64;     // 469
    const int nb2 = (NN + 255) / 256;  // 118
    const int nbe = (EE + 255) / 256;  // 3750

    // one-time (per call) zeroing of stats accumulators; folds re-zero after use
    hipMemsetAsync(ssum, 0, 512 * sizeof(float), stream);
    conv_wm1<<<32, blk, 0, stream>>>(Wm1, wm1h, wm1l);

    // ---- CSR build (once; reused by all 3 layers) ----
    hipMemsetAsync(deg, 0, NN * sizeof(int), stream);
    hist_deg<<<nbe, blk, 0, stream>>>(dst, deg);
    scan1<<<nb2, blk, 0, stream>>>(deg, rowptr, bsum);
    scan2<<<1, blk, 0, stream>>>(bsum, rowptr, nb2);
    scan3<<<nb2, blk, 0, stream>>>(rowptr, bsum, cursor);
    fill_csr<<<nbe, blk, 0, stream>>>(src, dst, cursor, csr_src);

    for (int l = 0; l < 3; ++l) {
        const float* xin = (l == 0) ? x : hbuf;
        int cin = (l == 0) ? IN_ : DD;

        gemm_tile<<<dim3(nb, 1), blk, 0, stream>>>(xin, cin, W1[l], cin, nullptr,
                                                   y1, 64, NN, cin, 2, ssum, ssq);
        fold_bn1_w2<<<1, 64, 0, stream>>>(ssum, ssq, g1[l], b1[l], a1p, c1p,
                                          W2[l], W2f, b2f, invN);

        gemm_tile<<<dim3(nb, 1), blk, 0, stream>>>(y1, 64, W2f, 64, b2f,
                                                   y2, 64, NN, 64, 2, ssum, ssq);
        fold_bn<<<1, 64, 0, stream>>>(ssum, ssq, g2[l], b2[l], a2p, c2p, 64, invN);

        gather_agg<<<(NN + 15) / 16, blk, 0, stream>>>(rowptr, csr_src, y2, a2p, c2p, agg);

        // y2 is dead after gather -> reuse its space for the bf16 pre-tiled Wp
        short* Wpb = (short*)y2;
        conv_wp<<<512, blk, 0, stream>>>(Wp[l], Wpb);

        bool st = (l < 2);
        fog_mfma<<<dim3(nb), dim3(512), 0, stream>>>(y1, a1p, c1p, agg, Wpb, hbuf, NN,
                                                     st ? ssum : nullptr, st ? ssq : nullptr,
                                                     st ? nullptr : sbuf);
        if (st) {
            fold_bn<<<1, 256, 0, stream>>>(ssum, ssq, gbn[l], bbn[l], ahp, chp, 256, invN);
            bn_relu_jk<<<(NN * DD / 4 + 255) / 256, blk, 0, stream>>>(
                (const float4*)hbuf, ahp, chp, (float4*)sbuf, (float4*)hbuf, l == 0 ? 0 : 1);
        }
    }

    // MLP head: hid = relu(s @ Wm1.T + bm1) via bf16x3 MFMA -> hbuf
    head_mfma<<<nb, dim3(512), 0, stream>>>(sbuf, wm1h, wm1l, bm1, hbuf, NN);
    mlp2_lsm<<<nb, blk, 0, stream>>>(hbuf, Wm2, bm2, (float*)d_out, NN);
}